// Round 2
// baseline (1812.594 us; speedup 1.0000x reference)
//
#include <hip/hip_runtime.h>
#include <hip/hip_bf16.h>
#include <cmath>

using bf16 = __hip_bfloat16;
typedef __attribute__((ext_vector_type(8))) short short8;
typedef __attribute__((ext_vector_type(4))) float floatx4;

__device__ __forceinline__ float bu2f(ushort u) { return __uint_as_float((unsigned)u << 16); }
__device__ __forceinline__ ushort f2bu(float f) {
  union { bf16 b; ushort u; } cv; cv.b = __float2bfloat16(f); return cv.u;
}

static constexpr int kT   = 4096;
static constexpr int kDim = 1024;
static constexpr float kScale   = 0.08838834764831845f;  // 1/sqrt(128)
static constexpr float kSelfVal = -5.0e4f;

// ---------------- dtype detector: bf16 vs fp32 inputs ----------------
__device__ __forceinline__ int sane_v(float f) { float a = fabsf(f); return (a > 1e-4f && a < 1e4f) ? 1 : 0; }

__global__ __launch_bounds__(256) void k_detect(const unsigned* __restrict__ x, int* __restrict__ flag) {
  __shared__ int cnt;
  int tid = threadIdx.x;
  if (tid == 0) cnt = 0;
  __syncthreads();
  int my = 0;
  const uint4* p = (const uint4*)x;
  for (int q = 0; q < 16; q++) {
    uint4 u = p[tid * 16 + q];
    unsigned w0 = u.x, w1 = u.y, w2 = u.z, w3 = u.w;
    my += sane_v(__uint_as_float(w0 << 16)) + sane_v(__uint_as_float(w0 & 0xffff0000u));
    my += sane_v(__uint_as_float(w1 << 16)) + sane_v(__uint_as_float(w1 & 0xffff0000u));
    my += sane_v(__uint_as_float(w2 << 16)) + sane_v(__uint_as_float(w2 & 0xffff0000u));
    my += sane_v(__uint_as_float(w3 << 16)) + sane_v(__uint_as_float(w3 & 0xffff0000u));
  }
  atomicAdd(&cnt, my);
  __syncthreads();
  if (tid == 0) flag[0] = (cnt >= 24576) ? 1 : 0;   // >=75% sane as bf16 -> bf16
}

// ---------------- small-param convert to canonical bf16 ----------------
__global__ __launch_bounds__(256) void k_cvt(const int* __restrict__ flag, const void* __restrict__ src,
                                             ushort* __restrict__ dst, int n) {
  int i = blockIdx.x * 256 + threadIdx.x;
  if (i >= n) return;
  dst[i] = (*flag) ? ((const ushort*)src)[i] : f2bu(((const float*)src)[i]);
}

// ---------------- init: x1 = x2 = float(x) ----------------
__global__ __launch_bounds__(256) void k_init_any(const int* __restrict__ flag, const void* __restrict__ x,
                                                  float* __restrict__ x1, float* __restrict__ x2) {
  int i = blockIdx.x * 1024 + threadIdx.x * 4;
  float4 f;
  if (*flag) {
    ushort4 u = *(const ushort4*)((const ushort*)x + i);
    f.x = bu2f(u.x); f.y = bu2f(u.y); f.z = bu2f(u.z); f.w = bu2f(u.w);
  } else {
    f = *(const float4*)((const float*)x + i);
  }
  *(float4*)(x1 + i) = f;
  *(float4*)(x2 + i) = f;
}

// ---------------- final: out = (x1 + x2) in input dtype ----------------
__global__ __launch_bounds__(256) void k_final_any(const int* __restrict__ flag, const float* __restrict__ x1,
                                                   const float* __restrict__ x2, void* __restrict__ out) {
  int i = blockIdx.x * 1024 + threadIdx.x * 4;
  float4 a = *(const float4*)(x1 + i);
  float4 b = *(const float4*)(x2 + i);
  float4 s; s.x = a.x + b.x; s.y = a.y + b.y; s.z = a.z + b.z; s.w = a.w + b.w;
  if (*flag) {
    ushort4 u; u.x = f2bu(s.x); u.y = f2bu(s.y); u.z = f2bu(s.z); u.w = f2bu(s.w);
    *(ushort4*)((ushort*)out + i) = u;
  } else {
    *(float4*)((float*)out + i) = s;
  }
}

// ---------------- layernorm: fp32 in -> bf16 out ----------------
__global__ __launch_bounds__(256) void k_ln(const float* __restrict__ x, const ushort* __restrict__ g,
                                            const ushort* __restrict__ be, ushort* __restrict__ out) {
  __shared__ float ws[4], ws2[4];
  int row = blockIdx.x, tid = threadIdx.x;
  const float* xr = x + (size_t)row * kDim + tid * 4;
  float4 v = *(const float4*)xr;
  float s  = v.x + v.y + v.z + v.w;
  float s2 = v.x*v.x + v.y*v.y + v.z*v.z + v.w*v.w;
  #pragma unroll
  for (int off = 32; off; off >>= 1) { s += __shfl_down(s, off); s2 += __shfl_down(s2, off); }
  int wave = tid >> 6, lane = tid & 63;
  if (lane == 0) { ws[wave] = s; ws2[wave] = s2; }
  __syncthreads();
  s  = ws[0] + ws[1] + ws[2] + ws[3];
  s2 = ws2[0] + ws2[1] + ws2[2] + ws2[3];
  float mean = s * (1.f/1024.f);
  float var  = fmaxf(s2 * (1.f/1024.f) - mean*mean, 0.f);
  float rstd = rsqrtf(var + 1e-5f);
  int cb = tid * 4;
  ushort* o = out + (size_t)row * kDim + cb;
  o[0] = f2bu((v.x - mean) * rstd * bu2f(g[cb+0]) + bu2f(be[cb+0]));
  o[1] = f2bu((v.y - mean) * rstd * bu2f(g[cb+1]) + bu2f(be[cb+1]));
  o[2] = f2bu((v.z - mean) * rstd * bu2f(g[cb+2]) + bu2f(be[cb+2]));
  o[3] = f2bu((v.w - mean) * rstd * bu2f(g[cb+3]) + bu2f(be[cb+3]));
}

// ---------------- weight transpose: in[K,N] -> out[N,K], dtype-flag on input ----------------
__global__ __launch_bounds__(256) void k_transpose_any(const int* __restrict__ flag, const void* __restrict__ in,
                                                       ushort* __restrict__ out, int K, int N) {
  __shared__ ushort tile[32][33];
  int isbf = *flag;
  int nb = blockIdx.x * 32, kb = blockIdx.y * 32;
  int tx = threadIdx.x & 31, ty = threadIdx.x >> 5;
  for (int r = ty; r < 32; r += 8) {
    size_t idx = (size_t)(kb + r) * N + nb + tx;
    tile[r][tx] = isbf ? ((const ushort*)in)[idx] : f2bu(((const float*)in)[idx]);
  }
  __syncthreads();
  for (int r = ty; r < 32; r += 8) out[(size_t)(nb + r) * K + kb + tx] = tile[tx][r];
}

// ---------------- GEMM: C = A[M,K] @ Bt[N,K]^T, canonical bf16 (ushort) operands ----------------
// mode 0: Cf = A@B (fp32 out)             mode 1: Cf += A@B + bias (fp32 accumulate)
// mode 2: Cb = bf16(gelu(A@B + bias))     mode 3: Cb = bf16(A@B)
__global__ __launch_bounds__(256) void k_gemm(const ushort* __restrict__ A, const ushort* __restrict__ Bt,
                                              const ushort* __restrict__ bias, float* __restrict__ Cf,
                                              ushort* __restrict__ Cb, int M, int N, int K, int mode) {
  __shared__ alignas(16) ushort As[128*32];
  __shared__ alignas(16) ushort Bs[128*32];
  const int tid = threadIdx.x;
  const int lane = tid & 63, wave = tid >> 6;
  const int m0 = blockIdx.y * 128, n0 = blockIdx.x * 128;
  const int wm = (wave & 1) * 64, wn = (wave >> 1) * 64;
  const int lr = lane & 15, lk = (lane >> 4) * 8;
  const int sr = tid >> 2, sc = (tid & 3) << 3;
  floatx4 acc[4][4];
  #pragma unroll
  for (int mi = 0; mi < 4; mi++)
    #pragma unroll
    for (int ni = 0; ni < 4; ni++) acc[mi][ni] = (floatx4){0.f, 0.f, 0.f, 0.f};

  for (int k0 = 0; k0 < K; k0 += 32) {
    __syncthreads();
    *(uint4*)&As[sr*32 + sc]      = *(const uint4*)&A [(size_t)(m0 + sr)      * K + k0 + sc];
    *(uint4*)&As[(sr+64)*32 + sc] = *(const uint4*)&A [(size_t)(m0 + sr + 64) * K + k0 + sc];
    *(uint4*)&Bs[sr*32 + sc]      = *(const uint4*)&Bt[(size_t)(n0 + sr)      * K + k0 + sc];
    *(uint4*)&Bs[(sr+64)*32 + sc] = *(const uint4*)&Bt[(size_t)(n0 + sr + 64) * K + k0 + sc];
    __syncthreads();
    short8 a[4], b[4];
    #pragma unroll
    for (int mi = 0; mi < 4; mi++) a[mi] = *(const short8*)&As[(wm + mi*16 + lr)*32 + lk];
    #pragma unroll
    for (int ni = 0; ni < 4; ni++) b[ni] = *(const short8*)&Bs[(wn + ni*16 + lr)*32 + lk];
    #pragma unroll
    for (int mi = 0; mi < 4; mi++)
      #pragma unroll
      for (int ni = 0; ni < 4; ni++)
        acc[mi][ni] = __builtin_amdgcn_mfma_f32_16x16x32_bf16(a[mi], b[ni], acc[mi][ni], 0, 0, 0);
  }
  #pragma unroll
  for (int mi = 0; mi < 4; mi++) {
    #pragma unroll
    for (int ni = 0; ni < 4; ni++) {
      int col = n0 + wn + ni*16 + lr;
      float bv = (mode == 1 || mode == 2) ? bu2f(bias[col]) : 0.f;
      #pragma unroll
      for (int q = 0; q < 4; q++) {
        int row = m0 + wm + mi*16 + (lane >> 4)*4 + q;
        float val = acc[mi][ni][q];
        if (mode == 0) {
          Cf[(size_t)row * N + col] = val;
        } else if (mode == 1) {
          Cf[(size_t)row * N + col] += val + bv;
        } else if (mode == 2) {
          float xg = val + bv;
          Cb[(size_t)row * N + col] = f2bu(0.5f * xg * (1.f + erff(xg * 0.70710678118654752f)));
        } else {
          Cb[(size_t)row * N + col] = f2bu(val);
        }
      }
    }
  }
}

// ---------------- bucket = argmax over [rotated, -rotated] ----------------
__global__ __launch_bounds__(64) void k_bucket(const float* __restrict__ qk, const ushort* __restrict__ rot,
                                               int* __restrict__ bkt) {
  __shared__ float qs[128];
  int id = blockIdx.x;
  int bh = id >> 12, t = id & 4095;
  int b = bh >> 3, hh = bh & 7;
  int lane = threadIdx.x;
  const float* qrow = qk + ((size_t)(b * kT + t)) * kDim + hh * 128;
  qs[lane]      = qrow[lane];
  qs[lane + 64] = qrow[lane + 64];
  __syncthreads();
  #pragma unroll
  for (int hash = 0; hash < 4; hash++) {
    int i = lane & 31;
    float acc = 0.f;
    for (int f = 0; f < 128; f++) acc += qs[f] * bu2f(rot[(f*4 + hash)*32 + i]);
    float v; int idx;
    if (-acc > acc) { v = -acc; idx = i + 32; } else { v = acc; idx = i; }
    #pragma unroll
    for (int off = 16; off; off >>= 1) {
      float ov = __shfl_down(v, off);
      int   oi = __shfl_down(idx, off);
      if (ov > v || (ov == v && oi < idx)) { v = ov; idx = oi; }
    }
    if (lane == 0) bkt[(bh*4 + hash)*4096 + t] = idx;
  }
}

// ---------------- stable counting sort per (bh,hash): 4096 tokens, 64 buckets ----------------
__global__ __launch_bounds__(256) void k_sort(const int* __restrict__ bkt, int* __restrict__ st) {
  __shared__ unsigned char  hist[64*256];
  __shared__ unsigned short offs[64*256];
  __shared__ int base[64];
  int tid = threadIdx.x, grp = blockIdx.x;
  const int* bk = bkt + grp * 4096;
  for (int i = tid; i < 64*256; i += 256) hist[i] = 0;
  __syncthreads();
  int myb[16];
  #pragma unroll
  for (int j = 0; j < 16; j++) {
    myb[j] = bk[tid*16 + j];
    hist[myb[j]*256 + tid] += 1;   // private column, no race
  }
  __syncthreads();
  if (tid < 64) {
    int run = 0;
    for (int t = 0; t < 256; t++) { offs[tid*256 + t] = (unsigned short)run; run += hist[tid*256 + t]; }
    base[tid] = run;
  }
  __syncthreads();
  if (tid == 0) {
    int run = 0;
    for (int b2 = 0; b2 < 64; b2++) { int c = base[b2]; base[b2] = run; run += c; }
  }
  __syncthreads();
  #pragma unroll
  for (int j = 0; j < 16; j++) {
    int b2 = myb[j];
    int r = 0;
    for (int jj = 0; jj < j; jj++) r += (myb[jj] == b2) ? 1 : 0;
    st[grp*4096 + base[b2] + (int)offs[b2*256 + tid] + r] = tid*16 + j;
  }
}

// ---------------- chunked LSH attention: one block per (bh, chunk) ----------------
__global__ __launch_bounds__(256) void k_attn(const float* __restrict__ qk, const ushort* __restrict__ vbuf,
                                              const int* __restrict__ st, ushort* __restrict__ o_r,
                                              float* __restrict__ lse_r) {
  __shared__ alignas(16) ushort KV[128*136];   // phase1-2: raw K rows; phase3+: V^T [d][j]
  __shared__ alignas(16) ushort Ps[64*136];    // logits -> P
  __shared__ float rnorm[128];
  __shared__ int   kposs[128];
  __shared__ float red1[64*4];
  __shared__ float red2[64*4];
  __shared__ float lrow[64];

  const int tid = threadIdx.x;
  const int bid = blockIdx.x;
  const int bh = bid >> 8;
  const int c  = bid & 255;
  const int h  = c >> 6;
  const int cprev = (c + 255) & 255;
  const int b  = bh >> 3, hh = bh & 7;
  const int lane = tid & 63, wave = tid >> 6;
  const int lr = lane & 15, lk = (lane >> 4) * 8;

  // phase 1: stage raw K rows (0..63 = own chunk = queries; 64..127 = prev chunk)
  {
    int j = tid >> 1, half = tid & 1;
    int slot = (j < 64) ? (c*64 + j) : (cprev*64 + (j - 64));
    int pos = st[bh*16384 + slot];
    if (half == 0) kposs[j] = pos;
    const float* src = qk + ((size_t)(b * kT + pos)) * kDim + hh*128 + half*64;
    float ss = 0.f;
    #pragma unroll
    for (int i2 = 0; i2 < 64; i2 += 4) {
      float4 f = *(const float4*)(src + i2);
      ss += f.x*f.x + f.y*f.y + f.z*f.z + f.w*f.w;
      ushort* dst = &KV[j*136 + half*64 + i2];
      dst[0] = f2bu(f.x); dst[1] = f2bu(f.y); dst[2] = f2bu(f.z); dst[3] = f2bu(f.w);
    }
    ss += __shfl_xor(ss, 1);
    if (half == 0) rnorm[j] = 1.f / fmaxf(sqrtf(ss), 1e-12f);
  }
  __syncthreads();

  // phase 2: dots = Q K^T * scale / |k|, self-mask; wave w covers kv cols [w*32, w*32+32)
  {
    floatx4 acc[4][2];
    #pragma unroll
    for (int mi = 0; mi < 4; mi++) { acc[mi][0] = (floatx4){0,0,0,0}; acc[mi][1] = (floatx4){0,0,0,0}; }
    #pragma unroll
    for (int ks = 0; ks < 4; ks++) {
      short8 a[4], bb[2];
      #pragma unroll
      for (int mi = 0; mi < 4; mi++) a[mi]  = *(const short8*)&KV[(mi*16 + lr)*136 + ks*32 + lk];
      #pragma unroll
      for (int ni = 0; ni < 2; ni++) bb[ni] = *(const short8*)&KV[(wave*32 + ni*16 + lr)*136 + ks*32 + lk];
      #pragma unroll
      for (int mi = 0; mi < 4; mi++)
        #pragma unroll
        for (int ni = 0; ni < 2; ni++)
          acc[mi][ni] = __builtin_amdgcn_mfma_f32_16x16x32_bf16(a[mi], bb[ni], acc[mi][ni], 0, 0, 0);
    }
    #pragma unroll
    for (int mi = 0; mi < 4; mi++) {
      #pragma unroll
      for (int ni = 0; ni < 2; ni++) {
        int col = wave*32 + ni*16 + lr;
        float rn = rnorm[col] * kScale;
        int cpos = kposs[col];
        #pragma unroll
        for (int q = 0; q < 4; q++) {
          int row = mi*16 + (lane >> 4)*4 + q;
          float val = acc[mi][ni][q] * rn;
          if (cpos == kposs[row]) val = kSelfVal;
          Ps[row*136 + col] = f2bu(val);
        }
      }
    }
  }
  __syncthreads();

  // phase 3a: stage V transposed into KV (Vt[d][j]); V is canonical bf16
  {
    int j = tid >> 1, half = tid & 1;
    int pos = kposs[j];
    const ushort* src = vbuf + ((size_t)(b * kT + pos)) * kDim + hh*128 + half*64;
    #pragma unroll
    for (int i2 = 0; i2 < 64; i2 += 2) {
      unsigned u = *(const unsigned*)(src + i2);
      int d0 = half*64 + i2;
      KV[(d0+0)*136 + j] = (ushort)(u & 0xffffu);
      KV[(d0+1)*136 + j] = (ushort)(u >> 16);
    }
  }

  // phase 3b: softmax on Ps rows, 4 threads per row (clamped exp: NaN-proof)
  {
    int i = tid >> 2, part = tid & 3;
    const int jb = part * 32;
    float m = -1e30f;
    for (int j2 = 0; j2 < 32; j2++) m = fmaxf(m, bu2f(Ps[i*136 + jb + j2]));
    red1[i*4 + part] = m;
    __syncthreads();
    m = fmaxf(fmaxf(red1[i*4+0], red1[i*4+1]), fmaxf(red1[i*4+2], red1[i*4+3]));
    float ssum = 0.f;
    for (int j2 = 0; j2 < 32; j2++) {
      float arg = fmaxf(fminf(bu2f(Ps[i*136 + jb + j2]) - m, 0.f), -80.f);
      float p = __expf(arg);
      ssum += p;
      Ps[i*136 + jb + j2] = f2bu(p);
    }
    red2[i*4 + part] = ssum;
    __syncthreads();
    if (part == 0) {
      float l = fmaxf(red2[i*4+0] + red2[i*4+1] + red2[i*4+2] + red2[i*4+3], 1e-20f);
      lrow[i] = l;
      lse_r[(size_t)(bh*4 + h)*4096 + kposs[i]] = m + __logf(l);
    }
  }
  __syncthreads();

  // phase 4: O = P V; wave w covers d cols [w*32, w*32+32)
  {
    floatx4 acc[4][2];
    #pragma unroll
    for (int mi = 0; mi < 4; mi++) { acc[mi][0] = (floatx4){0,0,0,0}; acc[mi][1] = (floatx4){0,0,0,0}; }
    #pragma unroll
    for (int ks = 0; ks < 4; ks++) {
      short8 a[4], bb[2];
      #pragma unroll
      for (int mi = 0; mi < 4; mi++) a[mi]  = *(const short8*)&Ps[(mi*16 + lr)*136 + ks*32 + lk];
      #pragma unroll
      for (int ni = 0; ni < 2; ni++) bb[ni] = *(const short8*)&KV[(wave*32 + ni*16 + lr)*136 + ks*32 + lk];
      #pragma unroll
      for (int mi = 0; mi < 4; mi++)
        #pragma unroll
        for (int ni = 0; ni < 2; ni++)
          acc[mi][ni] = __builtin_amdgcn_mfma_f32_16x16x32_bf16(a[mi], bb[ni], acc[mi][ni], 0, 0, 0);
    }
    #pragma unroll
    for (int mi = 0; mi < 4; mi++) {
      #pragma unroll
      for (int ni = 0; ni < 2; ni++) {
        int d = wave*32 + ni*16 + lr;
        #pragma unroll
        for (int q = 0; q < 4; q++) {
          int row = mi*16 + (lane >> 4)*4 + q;
          float o = acc[mi][ni][q] / lrow[row];
          o_r[((size_t)(bh*4 + h)*4096 + kposs[row])*128 + d] = f2bu(o);
        }
      }
    }
  }
}

// ---------------- combine hash rounds ----------------
__global__ __launch_bounds__(256) void k_combine(const ushort* __restrict__ o_r, const float* __restrict__ lse_r,
                                                 ushort* __restrict__ attnbf) {
  int rid = blockIdx.x * 2 + (threadIdx.x >> 7);
  int d = threadIdx.x & 127;
  int bh = rid >> 12, t = rid & 4095;
  int b = bh >> 3, hh = bh & 7;
  size_t base = (size_t)bh * 16384 + t;
  float l0 = lse_r[base], l1 = lse_r[base + 4096], l2 = lse_r[base + 8192], l3 = lse_r[base + 12288];
  float M = fmaxf(fmaxf(l0, l1), fmaxf(l2, l3));
  float e0 = __expf(fmaxf(fminf(l0 - M, 0.f), -80.f));
  float e1 = __expf(fmaxf(fminf(l1 - M, 0.f), -80.f));
  float e2 = __expf(fmaxf(fminf(l2 - M, 0.f), -80.f));
  float e3 = __expf(fmaxf(fminf(l3 - M, 0.f), -80.f));
  float inv = 1.f / (e0 + e1 + e2 + e3);
  float o = e0 * bu2f(o_r[(base         )*128 + d]) + e1 * bu2f(o_r[(base +  4096)*128 + d])
          + e2 * bu2f(o_r[(base +  8192)*128 + d]) + e3 * bu2f(o_r[(base + 12288)*128 + d]);
  attnbf[((size_t)b * kT + t) * kDim + hh*128 + d] = f2bu(o * inv);
}

extern "C" void kernel_launch(void* const* d_in, const int* in_sizes, int n_in,
                              void* d_out, int out_size, void* d_ws, size_t ws_size,
                              hipStream_t stream) {
  (void)in_sizes; (void)n_in; (void)out_size; (void)ws_size;
  const void* x     = d_in[0];
  const void* ln1_g = d_in[1];
  const void* ln1_b = d_in[2];
  const void* Wqk   = d_in[3];
  const void* Wv    = d_in[4];
  const void* Wo    = d_in[5];
  const void* bo    = d_in[6];
  const void* ln2_g = d_in[7];
  const void* ln2_b = d_in[8];
  const void* W1    = d_in[9];
  const void* b1    = d_in[10];
  const void* W2    = d_in[11];
  const void* b2    = d_in[12];
  const void* rot   = d_in[13];

  char* w = (char*)d_ws;
  int*    flag = (int*)w;    w += 256;
  ushort* prm  = (ushort*)w; w += 131072;   // canonical small params (bf16)
  float* x1  = (float*)w;  w += 33554432;
  float* x2  = (float*)w;  w += 33554432;
  float* qk  = (float*)w;  w += 33554432;
  ushort* vbb = (ushort*)w; w += 16777216;
  ushort* xbf = (ushort*)w; w += 16777216;   // LN out / attn-combined
  ushort* orb = (ushort*)w; w += 67108864;   // per-round O, reused as gelu(ff1)
  float* lse = (float*)w;  w += 1048576;
  int*   bkt = (int*)w;    w += 1048576;
  int*   stb = (int*)w;    w += 1048576;
  ushort* wtA = (ushort*)w; w += 2097152;    // Wqk^T
  ushort* wtB = (ushort*)w; w += 2097152;    // Wv^T
  ushort* wtC = (ushort*)w; w += 2097152;    // Wo^T
  ushort* wt1 = (ushort*)w; w += 8388608;    // W1^T
  ushort* wt2 = (ushort*)w; w += 8388608;    // W2^T

  // canonical small-param element offsets
  ushort* pLN1G = prm + 0;     ushort* pLN1B = prm + 2048;
  ushort* pBO   = prm + 4096;  ushort* pLN2G = prm + 6144;
  ushort* pLN2B = prm + 8192;  ushort* pB1   = prm + 10240;
  ushort* pB2   = prm + 18432; ushort* pROT  = prm + 20480;

  k_detect<<<1, 256, 0, stream>>>((const unsigned*)x, flag);
  k_cvt<<<8,   256, 0, stream>>>(flag, ln1_g, pLN1G, 2048);
  k_cvt<<<8,   256, 0, stream>>>(flag, ln1_b, pLN1B, 2048);
  k_cvt<<<8,   256, 0, stream>>>(flag, bo,    pBO,   2048);
  k_cvt<<<8,   256, 0, stream>>>(flag, ln2_g, pLN2G, 2048);
  k_cvt<<<8,   256, 0, stream>>>(flag, ln2_b, pLN2B, 2048);
  k_cvt<<<32,  256, 0, stream>>>(flag, b1,    pB1,   8192);
  k_cvt<<<8,   256, 0, stream>>>(flag, b2,    pB2,   2048);
  k_cvt<<<128, 256, 0, stream>>>(flag, rot,   pROT,  32768);
  k_init_any<<<8192, 256, 0, stream>>>(flag, x, x1, x2);

  for (int d = 0; d < 2; d++) {
    size_t o1 = (size_t)d * 1024 * 1024, o4 = (size_t)d * 1024 * 4096;
    const void* wqk = (const void*)((const char*)Wqk + 0);  // dtype-dependent offset below
    // byte offsets depend on dtype; pass element-offset pointers for BOTH candidate dtypes:
    // we use a helper lambda-free approach: compute both and let k_transpose_any's flag pick.
    // Since element offsets are equal, offset in BYTES differs; handle by computing the two
    // pointers and passing the right one is impossible host-side. Instead transpose reads
    // from base + element offset internally -> simplest: pass base and element offset via N,K
    // trick. We instead transpose the FULL depth-2 arrays once (d loop handled by offsets into
    // the transposed outputs is wrong) -> so: do per-depth transposes with element offsets
    // applied per dtype inside the kernel by passing both pointers:
    (void)wqk;
    const char* pWqk_b = (const char*)Wqk;  // bf16 base
    // Per-depth source pointers for both dtype candidates:
    // bf16: base + o*2 ; fp32: base + o*4. k_transpose_any reads via flag, so we must pass a
    // pointer valid for BOTH. Trick: pass base pointer and fold the depth offset into the
    // index math by launching on the full array but restricting blocks -- simpler: transpose
    // both depths in one launch by treating K as 2*K rows? W is [2,K,N]; rows (d*K+k). So:
    // transpose the full [2K, N] -> [N, 2K]? That changes output layout. Cleanest: two
    // pre-offset pointers, one per dtype, chosen by a tiny dispatch: launch kernel with BOTH
    // pointers and flag picks. Do that.
    (void)pWqk_b; (void)o1; (void)o4;
    break;
  }

  // ---- per-depth transposes with dual-dtype source pointers ----
  auto xpose = [&](const void* base, ushort* dst, int K, int N, int d, dim3 grid) {
    const void* src_bf = (const void*)((const char*)base + (size_t)d * K * N * 2);
    const void* src_f  = (const void*)((const char*)base + (size_t)d * K * N * 4);
    // k_transpose_any picks via flag; we need ONE pointer. Use a dual-pointer kernel instead.
    (void)src_bf; (void)src_f; (void)dst; (void)grid;
  };
  (void)xpose;

  for (int d = 0; d < 2; d++) {
    // dual-dtype: pass both byte-offset pointers; kernel selects with flag
    extern __global__ void k_transpose2(const int*, const void*, const void*, ushort*, int, int);
    k_transpose2<<<dim3(32, 32),  256, 0, stream>>>(flag,
        (const char*)Wqk + (size_t)d*1048576*2, (const char*)Wqk + (size_t)d*1048576*4, wtA, 1024, 1024);
    k_transpose2<<<dim3(32, 32),  256, 0, stream>>>(flag,
        (const char*)Wv  + (size_t)d*1048576*2, (const char*)Wv  + (size_t)d*1048576*4, wtB, 1024, 1024);
    k_transpose2<<<dim3(32, 32),  256, 0, stream>>>(flag,
        (const char*)Wo  + (size_t)d*1048576*2, (const char*)Wo  + (size_t)d*1048576*4, wtC, 1024, 1024);
    k_transpose2<<<dim3(128, 32), 256, 0, stream>>>(flag,
        (const char*)W1  + (size_t)d*4194304*2, (const char*)W1  + (size_t)d*4194304*4, wt1, 1024, 4096);
    k_transpose2<<<dim3(32, 128), 256, 0, stream>>>(flag,
        (const char*)W2  + (size_t)d*4194304*2, (const char*)W2  + (size_t)d*4194304*4, wt2, 4096, 1024);

    k_ln<<<8192, 256, 0, stream>>>(x2, pLN1G + d*1024, pLN1B + d*1024, xbf);
    k_gemm<<<dim3(8, 64), 256, 0, stream>>>(xbf, wtA, nullptr, qk, nullptr, 8192, 1024, 1024, 0);
    k_gemm<<<dim3(8, 64), 256, 0, stream>>>(xbf, wtB, nullptr, nullptr, vbb, 8192, 1024, 1024, 3);
    k_bucket<<<65536, 64, 0, stream>>>(qk, pROT + (size_t)d * 16384, bkt);
    k_sort<<<64, 256, 0, stream>>>(bkt, stb);
    k_attn<<<4096, 256, 0, stream>>>(qk, vbb, stb, orb, lse);
    k_combine<<<32768, 256, 0, stream>>>(orb, lse, xbf);
    k_gemm<<<dim3(8, 64), 256, 0, stream>>>(xbf, wtC, pBO + d*1024, x1, nullptr, 8192, 1024, 1024, 1);
    k_ln<<<8192, 256, 0, stream>>>(x1, pLN2G + d*1024, pLN2B + d*1024, xbf);
    k_gemm<<<dim3(32, 64), 256, 0, stream>>>(xbf, wt1, pB1 + d*4096, nullptr, orb, 8192, 4096, 1024, 2);
    k_gemm<<<dim3(8, 64), 256, 0, stream>>>(orb, wt2, pB2 + d*1024, x2, nullptr, 8192, 1024, 4096, 1);
  }
  k_final_any<<<8192, 256, 0, stream>>>(flag, x1, x2, d_out);
}

// dual-dtype transpose: src_bf used when *flag==1, src_f when 0
__global__ __launch_bounds__(256) void k_transpose2(const int* __restrict__ flag, const void* __restrict__ src_bf,
                                                    const void* __restrict__ src_f, ushort* __restrict__ out,
                                                    int K, int N) {
  __shared__ ushort tile[32][33];
  int isbf = *flag;
  int nb = blockIdx.x * 32, kb = blockIdx.y * 32;
  int tx = threadIdx.x & 31, ty = threadIdx.x >> 5;
  for (int r = ty; r < 32; r += 8) {
    size_t idx = (size_t)(kb + r) * N + nb + tx;
    tile[r][tx] = isbf ? ((const ushort*)src_bf)[idx] : f2bu(((const float*)src_f)[idx]);
  }
  __syncthreads();
  for (int r = ty; r < 32; r += 8) out[(size_t)(nb + r) * K + kb + tx] = tile[tx][r];
}

// Round 5
// 1438.678 us; speedup vs baseline: 1.2599x; 1.2599x over previous
//
#include <hip/hip_runtime.h>
#include <hip/hip_bf16.h>
#include <cmath>

using bf16 = __hip_bfloat16;
typedef __attribute__((ext_vector_type(8))) short short8;
typedef __attribute__((ext_vector_type(4))) float floatx4;

__device__ __forceinline__ float bu2f(ushort u) { return __uint_as_float((unsigned)u << 16); }
__device__ __forceinline__ ushort f2bu(float f) {
  union { bf16 b; ushort u; } cv; cv.b = __float2bfloat16(f); return cv.u;
}
__device__ __forceinline__ void gl_lds16(const ushort* g, ushort* l) {
  __builtin_amdgcn_global_load_lds((const __attribute__((address_space(1))) unsigned*)g,
                                   (__attribute__((address_space(3))) unsigned*)l, 16, 0, 0);
}

static constexpr int kT   = 4096;
static constexpr int kDim = 1024;
static constexpr float kScale   = 0.08838834764831845f;  // 1/sqrt(128)
static constexpr float kSelfVal = -5.0e4f;

// ---------------- dtype detector: bf16 vs fp32 inputs ----------------
__device__ __forceinline__ int sane_v(float f) { float a = fabsf(f); return (a > 1e-4f && a < 1e4f) ? 1 : 0; }

__global__ __launch_bounds__(256) void k_detect(const unsigned* __restrict__ x, int* __restrict__ flag) {
  __shared__ int cnt;
  int tid = threadIdx.x;
  if (tid == 0) cnt = 0;
  __syncthreads();
  int my = 0;
  const uint4* p = (const uint4*)x;
  for (int q = 0; q < 16; q++) {
    uint4 u = p[tid * 16 + q];
    my += sane_v(__uint_as_float(u.x << 16)) + sane_v(__uint_as_float(u.x & 0xffff0000u));
    my += sane_v(__uint_as_float(u.y << 16)) + sane_v(__uint_as_float(u.y & 0xffff0000u));
    my += sane_v(__uint_as_float(u.z << 16)) + sane_v(__uint_as_float(u.z & 0xffff0000u));
    my += sane_v(__uint_as_float(u.w << 16)) + sane_v(__uint_as_float(u.w & 0xffff0000u));
  }
  atomicAdd(&cnt, my);
  __syncthreads();
  if (tid == 0) flag[0] = (cnt >= 24576) ? 1 : 0;
}

__global__ __launch_bounds__(256) void k_cvt(const int* __restrict__ flag, const void* __restrict__ src,
                                             ushort* __restrict__ dst, int n) {
  int i = blockIdx.x * 256 + threadIdx.x;
  if (i >= n) return;
  dst[i] = (*flag) ? ((const ushort*)src)[i] : f2bu(((const float*)src)[i]);
}

__global__ __launch_bounds__(256) void k_init_any(const int* __restrict__ flag, const void* __restrict__ x,
                                                  float* __restrict__ x1, float* __restrict__ x2) {
  int i = blockIdx.x * 1024 + threadIdx.x * 4;
  float4 f;
  if (*flag) {
    ushort4 u = *(const ushort4*)((const ushort*)x + i);
    f.x = bu2f(u.x); f.y = bu2f(u.y); f.z = bu2f(u.z); f.w = bu2f(u.w);
  } else {
    f = *(const float4*)((const float*)x + i);
  }
  *(float4*)(x1 + i) = f;
  *(float4*)(x2 + i) = f;
}

__global__ __launch_bounds__(256) void k_final_any(const int* __restrict__ flag, const float* __restrict__ x1,
                                                   const float* __restrict__ x2, void* __restrict__ out) {
  int i = blockIdx.x * 1024 + threadIdx.x * 4;
  float4 a = *(const float4*)(x1 + i);
  float4 b = *(const float4*)(x2 + i);
  float4 s; s.x = a.x + b.x; s.y = a.y + b.y; s.z = a.z + b.z; s.w = a.w + b.w;
  if (*flag) {
    ushort4 u; u.x = f2bu(s.x); u.y = f2bu(s.y); u.z = f2bu(s.z); u.w = f2bu(s.w);
    *(ushort4*)((ushort*)out + i) = u;
  } else {
    *(float4*)((float*)out + i) = s;
  }
}

// ---------------- layernorm: fp32 in -> bf16 out ----------------
__global__ __launch_bounds__(256) void k_ln(const float* __restrict__ x, const ushort* __restrict__ g,
                                            const ushort* __restrict__ be, ushort* __restrict__ out) {
  __shared__ float ws[4], ws2[4];
  int row = blockIdx.x, tid = threadIdx.x;
  const float* xr = x + (size_t)row * kDim + tid * 4;
  float4 v = *(const float4*)xr;
  float s  = v.x + v.y + v.z + v.w;
  float s2 = v.x*v.x + v.y*v.y + v.z*v.z + v.w*v.w;
  #pragma unroll
  for (int off = 32; off; off >>= 1) { s += __shfl_down(s, off); s2 += __shfl_down(s2, off); }
  int wave = tid >> 6, lane = tid & 63;
  if (lane == 0) { ws[wave] = s; ws2[wave] = s2; }
  __syncthreads();
  s  = ws[0] + ws[1] + ws[2] + ws[3];
  s2 = ws2[0] + ws2[1] + ws2[2] + ws2[3];
  float mean = s * (1.f/1024.f);
  float var  = fmaxf(s2 * (1.f/1024.f) - mean*mean, 0.f);
  float rstd = rsqrtf(var + 1e-5f);
  int cb = tid * 4;
  ushort* o = out + (size_t)row * kDim + cb;
  o[0] = f2bu((v.x - mean) * rstd * bu2f(g[cb+0]) + bu2f(be[cb+0]));
  o[1] = f2bu((v.y - mean) * rstd * bu2f(g[cb+1]) + bu2f(be[cb+1]));
  o[2] = f2bu((v.z - mean) * rstd * bu2f(g[cb+2]) + bu2f(be[cb+2]));
  o[3] = f2bu((v.w - mean) * rstd * bu2f(g[cb+3]) + bu2f(be[cb+3]));
}

// ---------------- dual-dtype weight transpose: in[K,N] -> out[N,K] ----------------
__global__ __launch_bounds__(256) void k_transpose2(const int* __restrict__ flag, const void* __restrict__ src_bf,
                                                    const void* __restrict__ src_f, ushort* __restrict__ out,
                                                    int K, int N) {
  __shared__ ushort tile[32][33];
  int isbf = *flag;
  int nb = blockIdx.x * 32, kb = blockIdx.y * 32;
  int tx = threadIdx.x & 31, ty = threadIdx.x >> 5;
  for (int r = ty; r < 32; r += 8) {
    size_t idx = (size_t)(kb + r) * N + nb + tx;
    tile[r][tx] = isbf ? ((const ushort*)src_bf)[idx] : f2bu(((const float*)src_f)[idx]);
  }
  __syncthreads();
  for (int r = ty; r < 32; r += 8) out[(size_t)(nb + r) * K + kb + tx] = tile[tx][r];
}

// ---------------- rot transpose: rot[k=128][n=128] -> rotT[n=128][k=128] ----------------
// BUG FIX (r3/r4): output idx = n*128 + k, so n = idx>>7, k = idx&127 (was swapped -> identity copy)
__global__ __launch_bounds__(256) void k_rot_t(const ushort* __restrict__ rot, ushort* __restrict__ rotT) {
  int tid = threadIdx.x;
  for (int idx = tid; idx < 16384; idx += 256) {
    int n = idx >> 7, k = idx & 127;
    rotT[idx] = rot[k * 128 + n];
  }
}

// ---------------- GEMM with global_load_lds staging ----------------
// mode 0: Cf = A@B   mode 1: Cf += A@B + bias   mode 2: Cb = bf16(gelu(A@B+bias))   mode 3: Cb = bf16(A@B)
__global__ __launch_bounds__(256) void k_gemm(const ushort* __restrict__ A, const ushort* __restrict__ Bt,
                                              const ushort* __restrict__ bias, float* __restrict__ Cf,
                                              ushort* __restrict__ Cb, int M, int N, int K, int mode) {
  __shared__ alignas(16) ushort As[128*32];
  __shared__ alignas(16) ushort Bs[128*32];
  const int tid = threadIdx.x;
  const int lane = tid & 63, wave = tid >> 6;
  const int m0 = blockIdx.y * 128, n0 = blockIdx.x * 128;
  const int wm = (wave & 1) * 64, wn = (wave >> 1) * 64;
  const int lr = lane & 15, lk = (lane >> 4) * 8;
  const int row = tid >> 2, c8 = (tid & 3) * 8;
  floatx4 acc[4][4];
  #pragma unroll
  for (int mi = 0; mi < 4; mi++)
    #pragma unroll
    for (int ni = 0; ni < 4; ni++) acc[mi][ni] = (floatx4){0.f, 0.f, 0.f, 0.f};

  const ushort* Ab = A  + (size_t)(m0 + row) * K + c8;
  const ushort* Ab2= A  + (size_t)(m0 + row + 64) * K + c8;
  const ushort* Bb = Bt + (size_t)(n0 + row) * K + c8;
  const ushort* Bb2= Bt + (size_t)(n0 + row + 64) * K + c8;
  ushort* lA0 = As + wave*512;
  ushort* lA1 = As + 2048 + wave*512;
  ushort* lB0 = Bs + wave*512;
  ushort* lB1 = Bs + 2048 + wave*512;

  for (int k0 = 0; k0 < K; k0 += 32) {
    __syncthreads();
    gl_lds16(Ab  + k0, lA0);
    gl_lds16(Ab2 + k0, lA1);
    gl_lds16(Bb  + k0, lB0);
    gl_lds16(Bb2 + k0, lB1);
    __syncthreads();
    short8 a[4], b[4];
    #pragma unroll
    for (int mi = 0; mi < 4; mi++) a[mi] = *(const short8*)&As[(wm + mi*16 + lr)*32 + lk];
    #pragma unroll
    for (int ni = 0; ni < 4; ni++) b[ni] = *(const short8*)&Bs[(wn + ni*16 + lr)*32 + lk];
    #pragma unroll
    for (int mi = 0; mi < 4; mi++)
      #pragma unroll
      for (int ni = 0; ni < 4; ni++)
        acc[mi][ni] = __builtin_amdgcn_mfma_f32_16x16x32_bf16(a[mi], b[ni], acc[mi][ni], 0, 0, 0);
  }
  #pragma unroll
  for (int mi = 0; mi < 4; mi++) {
    #pragma unroll
    for (int ni = 0; ni < 4; ni++) {
      int col = n0 + wn + ni*16 + lr;
      float bv = (mode == 1 || mode == 2) ? bu2f(bias[col]) : 0.f;
      #pragma unroll
      for (int q = 0; q < 4; q++) {
        int r2 = m0 + wm + mi*16 + (lane >> 4)*4 + q;
        float val = acc[mi][ni][q];
        if (mode == 0) {
          Cf[(size_t)r2 * N + col] = val;
        } else if (mode == 1) {
          Cf[(size_t)r2 * N + col] += val + bv;
        } else if (mode == 2) {
          float xg = val + bv;
          Cb[(size_t)r2 * N + col] = f2bu(0.5f * xg * (1.f + erff(xg * 0.70710678118654752f)));
        } else {
          Cb[(size_t)r2 * N + col] = f2bu(val);
        }
      }
    }
  }
}

// ---------------- MFMA bucket, split-precision (hi+lo) Q; in-register first-max argmax ----------------
__global__ __launch_bounds__(256) void k_bucket_mfma(const float* __restrict__ qk, const ushort* __restrict__ rotT,
                                                     int* __restrict__ bkt) {
  __shared__ alignas(16) ushort Bs[128*128];  // rotT [n][k]  32 KB
  __shared__ alignas(16) ushort Ah[64*128];   // Q hi         16 KB
  __shared__ alignas(16) ushort Al[64*128];   // Q lo         16 KB
  const int tid = threadIdx.x;
  const int lane = tid & 63, wave = tid >> 6;
  const int lr = lane & 15, lk = (lane >> 4) * 8;
  const int tt = blockIdx.x * 64;
  const int bh = blockIdx.y;
  const int b = bh >> 3, hh = bh & 7;

  {
    int r = tid >> 2, c0 = (tid & 3) * 32;
    const float* src = qk + ((size_t)(b * kT + tt + r)) * kDim + hh * 128 + c0;
    ushort* dh = &Ah[r * 128 + c0];
    ushort* dl = &Al[r * 128 + c0];
    #pragma unroll
    for (int i = 0; i < 32; i += 4) {
      float4 f = *(const float4*)(src + i);
      ushort h0 = f2bu(f.x), h1 = f2bu(f.y), h2 = f2bu(f.z), h3 = f2bu(f.w);
      dh[i+0] = h0; dh[i+1] = h1; dh[i+2] = h2; dh[i+3] = h3;
      dl[i+0] = f2bu(f.x - bu2f(h0)); dl[i+1] = f2bu(f.y - bu2f(h1));
      dl[i+2] = f2bu(f.z - bu2f(h2)); dl[i+3] = f2bu(f.w - bu2f(h3));
    }
  }
  {
    const uint4* src = (const uint4*)rotT;
    uint4* dst = (uint4*)Bs;
    for (int i = tid; i < 2048; i += 256) dst[i] = src[i];
  }
  __syncthreads();

  floatx4 acc[4][2];
  #pragma unroll
  for (int mi = 0; mi < 4; mi++) { acc[mi][0] = (floatx4){0,0,0,0}; acc[mi][1] = (floatx4){0,0,0,0}; }
  #pragma unroll
  for (int ks = 0; ks < 4; ks++) {
    short8 a[4], bb[2];
    #pragma unroll
    for (int ni = 0; ni < 2; ni++) bb[ni] = *(const short8*)&Bs[(wave*32 + ni*16 + lr)*128 + ks*32 + lk];
    #pragma unroll
    for (int mi = 0; mi < 4; mi++) a[mi] = *(const short8*)&Ah[(mi*16 + lr)*128 + ks*32 + lk];
    #pragma unroll
    for (int mi = 0; mi < 4; mi++)
      #pragma unroll
      for (int ni = 0; ni < 2; ni++)
        acc[mi][ni] = __builtin_amdgcn_mfma_f32_16x16x32_bf16(a[mi], bb[ni], acc[mi][ni], 0, 0, 0);
  }
  #pragma unroll
  for (int ks = 0; ks < 4; ks++) {
    short8 a[4], bb[2];
    #pragma unroll
    for (int ni = 0; ni < 2; ni++) bb[ni] = *(const short8*)&Bs[(wave*32 + ni*16 + lr)*128 + ks*32 + lk];
    #pragma unroll
    for (int mi = 0; mi < 4; mi++) a[mi] = *(const short8*)&Al[(mi*16 + lr)*128 + ks*32 + lk];
    #pragma unroll
    for (int mi = 0; mi < 4; mi++)
      #pragma unroll
      for (int ni = 0; ni < 2; ni++)
        acc[mi][ni] = __builtin_amdgcn_mfma_f32_16x16x32_bf16(a[mi], bb[ni], acc[mi][ni], 0, 0, 0);
  }

  #pragma unroll
  for (int mi = 0; mi < 4; mi++) {
    #pragma unroll
    for (int q = 0; q < 4; q++) {
      float v0 = acc[mi][0][q];
      float v1 = acc[mi][1][q];
      float best = v0; int bidx = lr;
      if (v1  > best) { best = v1;  bidx = 16 + lr; }
      if (-v0 > best) { best = -v0; bidx = 32 + lr; }
      if (-v1 > best) { best = -v1; bidx = 48 + lr; }
      #pragma unroll
      for (int m = 1; m <= 8; m <<= 1) {
        float ov = __shfl_xor(best, m);
        int   oi = __shfl_xor(bidx, m);
        if (ov > best || (ov == best && oi < bidx)) { best = ov; bidx = oi; }
      }
      if (lr == 0) {
        int row = mi*16 + ((lane >> 4) & 3)*4 + q;
        bkt[(bh*4 + wave)*4096 + tt + row] = bidx;
      }
    }
  }
}

// ---------------- stable counting sort per (bh,hash) ----------------
__global__ __launch_bounds__(256) void k_sort(const int* __restrict__ bkt, int* __restrict__ st) {
  __shared__ unsigned char  hist[64*256];
  __shared__ unsigned short offs[64*256];
  __shared__ int base[64];
  int tid = threadIdx.x, grp = blockIdx.x;
  const int* bk = bkt + grp * 4096;
  for (int i = tid; i < 64*256; i += 256) hist[i] = 0;
  __syncthreads();
  int myb[16];
  #pragma unroll
  for (int j = 0; j < 16; j++) {
    myb[j] = bk[tid*16 + j];
    hist[myb[j]*256 + tid] += 1;
  }
  __syncthreads();
  if (tid < 64) {
    int run = 0;
    for (int t = 0; t < 256; t++) { offs[tid*256 + t] = (unsigned short)run; run += hist[tid*256 + t]; }
    base[tid] = run;
  }
  __syncthreads();
  if (tid == 0) {
    int run = 0;
    for (int b2 = 0; b2 < 64; b2++) { int c = base[b2]; base[b2] = run; run += c; }
  }
  __syncthreads();
  #pragma unroll
  for (int j = 0; j < 16; j++) {
    int b2 = myb[j];
    int r = 0;
    for (int jj = 0; jj < j; jj++) r += (myb[jj] == b2) ? 1 : 0;
    st[grp*4096 + base[b2] + (int)offs[b2*256 + tid] + r] = tid*16 + j;
  }
}

// ---------------- chunked LSH attention ----------------
__global__ __launch_bounds__(256) void k_attn(const float* __restrict__ qk, const ushort* __restrict__ vbuf,
                                              const int* __restrict__ st, ushort* __restrict__ o_r,
                                              float* __restrict__ lse_r) {
  __shared__ alignas(16) ushort KV[128*136];
  __shared__ alignas(16) ushort Ps[64*136];
  __shared__ float rnorm[128];
  __shared__ int   kposs[128];
  __shared__ float red1[64*4];
  __shared__ float red2[64*4];
  __shared__ float lrow[64];

  const int tid = threadIdx.x;
  const int bid = blockIdx.x;
  const int bh = bid >> 8;
  const int c  = bid & 255;
  const int h  = c >> 6;
  const int cprev = (c + 255) & 255;
  const int b  = bh >> 3, hh = bh & 7;
  const int lane = tid & 63, wave = tid >> 6;
  const int lr = lane & 15, lk = (lane >> 4) * 8;

  {
    int j = tid >> 1, half = tid & 1;
    int slot = (j < 64) ? (c*64 + j) : (cprev*64 + (j - 64));
    int pos = st[bh*16384 + slot];
    if (half == 0) kposs[j] = pos;
    const float* src = qk + ((size_t)(b * kT + pos)) * kDim + hh*128 + half*64;
    float ss = 0.f;
    #pragma unroll
    for (int i2 = 0; i2 < 64; i2 += 4) {
      float4 f = *(const float4*)(src + i2);
      ss += f.x*f.x + f.y*f.y + f.z*f.z + f.w*f.w;
      ushort* dst = &KV[j*136 + half*64 + i2];
      dst[0] = f2bu(f.x); dst[1] = f2bu(f.y); dst[2] = f2bu(f.z); dst[3] = f2bu(f.w);
    }
    ss += __shfl_xor(ss, 1);
    if (half == 0) rnorm[j] = 1.f / fmaxf(sqrtf(ss), 1e-12f);
  }
  __syncthreads();

  {
    floatx4 acc[4][2];
    #pragma unroll
    for (int mi = 0; mi < 4; mi++) { acc[mi][0] = (floatx4){0,0,0,0}; acc[mi][1] = (floatx4){0,0,0,0}; }
    #pragma unroll
    for (int ks = 0; ks < 4; ks++) {
      short8 a[4], bb[2];
      #pragma unroll
      for (int mi = 0; mi < 4; mi++) a[mi]  = *(const short8*)&KV[(mi*16 + lr)*136 + ks*32 + lk];
      #pragma unroll
      for (int ni = 0; ni < 2; ni++) bb[ni] = *(const short8*)&KV[(wave*32 + ni*16 + lr)*136 + ks*32 + lk];
      #pragma unroll
      for (int mi = 0; mi < 4; mi++)
        #pragma unroll
        for (int ni = 0; ni < 2; ni++)
          acc[mi][ni] = __builtin_amdgcn_mfma_f32_16x16x32_bf16(a[mi], bb[ni], acc[mi][ni], 0, 0, 0);
    }
    #pragma unroll
    for (int mi = 0; mi < 4; mi++) {
      #pragma unroll
      for (int ni = 0; ni < 2; ni++) {
        int col = wave*32 + ni*16 + lr;
        float rn = rnorm[col] * kScale;
        int cpos = kposs[col];
        #pragma unroll
        for (int q = 0; q < 4; q++) {
          int row = mi*16 + (lane >> 4)*4 + q;
          float val = acc[mi][ni][q] * rn;
          if (cpos == kposs[row]) val = kSelfVal;
          Ps[row*136 + col] = f2bu(val);
        }
      }
    }
  }
  __syncthreads();

  {
    int j = tid >> 1, half = tid & 1;
    int pos = kposs[j];
    const ushort* src = vbuf + ((size_t)(b * kT + pos)) * kDim + hh*128 + half*64;
    #pragma unroll
    for (int i2 = 0; i2 < 64; i2 += 2) {
      unsigned u = *(const unsigned*)(src + i2);
      int d0 = half*64 + i2;
      KV[(d0+0)*136 + j] = (ushort)(u & 0xffffu);
      KV[(d0+1)*136 + j] = (ushort)(u >> 16);
    }
  }

  {
    int i = tid >> 2, part = tid & 3;
    const int jb = part * 32;
    float m = -1e30f;
    for (int j2 = 0; j2 < 32; j2++) m = fmaxf(m, bu2f(Ps[i*136 + jb + j2]));
    red1[i*4 + part] = m;
    __syncthreads();
    m = fmaxf(fmaxf(red1[i*4+0], red1[i*4+1]), fmaxf(red1[i*4+2], red1[i*4+3]));
    float ssum = 0.f;
    for (int j2 = 0; j2 < 32; j2++) {
      float arg = fmaxf(fminf(bu2f(Ps[i*136 + jb + j2]) - m, 0.f), -80.f);
      float p = __expf(arg);
      ssum += p;
      Ps[i*136 + jb + j2] = f2bu(p);
    }
    red2[i*4 + part] = ssum;
    __syncthreads();
    if (part == 0) {
      float l = fmaxf(red2[i*4+0] + red2[i*4+1] + red2[i*4+2] + red2[i*4+3], 1e-20f);
      lrow[i] = l;
      lse_r[(size_t)(bh*4 + h)*4096 + kposs[i]] = m + __logf(l);
    }
  }
  __syncthreads();

  {
    floatx4 acc[4][2];
    #pragma unroll
    for (int mi = 0; mi < 4; mi++) { acc[mi][0] = (floatx4){0,0,0,0}; acc[mi][1] = (floatx4){0,0,0,0}; }
    #pragma unroll
    for (int ks = 0; ks < 4; ks++) {
      short8 a[4], bb[2];
      #pragma unroll
      for (int mi = 0; mi < 4; mi++) a[mi]  = *(const short8*)&Ps[(mi*16 + lr)*136 + ks*32 + lk];
      #pragma unroll
      for (int ni = 0; ni < 2; ni++) bb[ni] = *(const short8*)&KV[(wave*32 + ni*16 + lr)*136 + ks*32 + lk];
      #pragma unroll
      for (int mi = 0; mi < 4; mi++)
        #pragma unroll
        for (int ni = 0; ni < 2; ni++)
          acc[mi][ni] = __builtin_amdgcn_mfma_f32_16x16x32_bf16(a[mi], bb[ni], acc[mi][ni], 0, 0, 0);
    }
    #pragma unroll
    for (int mi = 0; mi < 4; mi++) {
      #pragma unroll
      for (int ni = 0; ni < 2; ni++) {
        int d = wave*32 + ni*16 + lr;
        #pragma unroll
        for (int q = 0; q < 4; q++) {
          int row = mi*16 + (lane >> 4)*4 + q;
          float o = acc[mi][ni][q] / lrow[row];
          o_r[((size_t)(bh*4 + h)*4096 + kposs[row])*128 + d] = f2bu(o);
        }
      }
    }
  }
}

// ---------------- combine hash rounds ----------------
__global__ __launch_bounds__(256) void k_combine(const ushort* __restrict__ o_r, const float* __restrict__ lse_r,
                                                 ushort* __restrict__ attnbf) {
  int rid = blockIdx.x * 2 + (threadIdx.x >> 7);
  int d = threadIdx.x & 127;
  int bh = rid >> 12, t = rid & 4095;
  int b = bh >> 3, hh = bh & 7;
  size_t base = (size_t)bh * 16384 + t;
  float l0 = lse_r[base], l1 = lse_r[base + 4096], l2 = lse_r[base + 8192], l3 = lse_r[base + 12288];
  float M = fmaxf(fmaxf(l0, l1), fmaxf(l2, l3));
  float e0 = __expf(fmaxf(fminf(l0 - M, 0.f), -80.f));
  float e1 = __expf(fmaxf(fminf(l1 - M, 0.f), -80.f));
  float e2 = __expf(fmaxf(fminf(l2 - M, 0.f), -80.f));
  float e3 = __expf(fmaxf(fminf(l3 - M, 0.f), -80.f));
  float inv = 1.f / (e0 + e1 + e2 + e3);
  float o = e0 * bu2f(o_r[(base         )*128 + d]) + e1 * bu2f(o_r[(base +  4096)*128 + d])
          + e2 * bu2f(o_r[(base +  8192)*128 + d]) + e3 * bu2f(o_r[(base + 12288)*128 + d]);
  attnbf[((size_t)b * kT + t) * kDim + hh*128 + d] = f2bu(o * inv);
}

extern "C" void kernel_launch(void* const* d_in, const int* in_sizes, int n_in,
                              void* d_out, int out_size, void* d_ws, size_t ws_size,
                              hipStream_t stream) {
  (void)in_sizes; (void)n_in; (void)out_size; (void)ws_size;
  const void* x     = d_in[0];
  const void* ln1_g = d_in[1];
  const void* ln1_b = d_in[2];
  const void* Wqk   = d_in[3];
  const void* Wv    = d_in[4];
  const void* Wo    = d_in[5];
  const void* bo    = d_in[6];
  const void* ln2_g = d_in[7];
  const void* ln2_b = d_in[8];
  const void* W1    = d_in[9];
  const void* b1    = d_in[10];
  const void* W2    = d_in[11];
  const void* b2    = d_in[12];
  const void* rot   = d_in[13];

  char* w = (char*)d_ws;
  int*    flag = (int*)w;    w += 256;
  ushort* prm  = (ushort*)w; w += 131072;
  float* x1  = (float*)w;  w += 33554432;
  float* x2  = (float*)w;  w += 33554432;
  float* qk  = (float*)w;  w += 33554432;
  ushort* vbb = (ushort*)w; w += 16777216;
  ushort* xbf = (ushort*)w; w += 16777216;
  ushort* orb = (ushort*)w; w += 67108864;
  float* lse = (float*)w;  w += 1048576;
  int*   bkt = (int*)w;    w += 1048576;
  int*   stb = (int*)w;    w += 1048576;
  ushort* wtA = (ushort*)w; w += 2097152;
  ushort* wtB = (ushort*)w; w += 2097152;
  ushort* wtC = (ushort*)w; w += 2097152;
  ushort* wt1 = (ushort*)w; w += 8388608;
  ushort* wt2 = (ushort*)w; w += 8388608;
  ushort* rtT = (ushort*)w; w += 32768;

  ushort* pLN1G = prm + 0;     ushort* pLN1B = prm + 2048;
  ushort* pBO   = prm + 4096;  ushort* pLN2G = prm + 6144;
  ushort* pLN2B = prm + 8192;  ushort* pB1   = prm + 10240;
  ushort* pB2   = prm + 18432; ushort* pROT  = prm + 20480;

  k_detect<<<1, 256, 0, stream>>>((const unsigned*)x, flag);
  k_cvt<<<8,   256, 0, stream>>>(flag, ln1_g, pLN1G, 2048);
  k_cvt<<<8,   256, 0, stream>>>(flag, ln1_b, pLN1B, 2048);
  k_cvt<<<8,   256, 0, stream>>>(flag, bo,    pBO,   2048);
  k_cvt<<<8,   256, 0, stream>>>(flag, ln2_g, pLN2G, 2048);
  k_cvt<<<8,   256, 0, stream>>>(flag, ln2_b, pLN2B, 2048);
  k_cvt<<<32,  256, 0, stream>>>(flag, b1,    pB1,   8192);
  k_cvt<<<8,   256, 0, stream>>>(flag, b2,    pB2,   2048);
  k_cvt<<<128, 256, 0, stream>>>(flag, rot,   pROT,  32768);
  k_init_any<<<8192, 256, 0, stream>>>(flag, x, x1, x2);

  for (int d = 0; d < 2; d++) {
    k_transpose2<<<dim3(32, 32),  256, 0, stream>>>(flag,
        (const char*)Wqk + (size_t)d*1048576*2, (const char*)Wqk + (size_t)d*1048576*4, wtA, 1024, 1024);
    k_transpose2<<<dim3(32, 32),  256, 0, stream>>>(flag,
        (const char*)Wv  + (size_t)d*1048576*2, (const char*)Wv  + (size_t)d*1048576*4, wtB, 1024, 1024);
    k_transpose2<<<dim3(32, 32),  256, 0, stream>>>(flag,
        (const char*)Wo  + (size_t)d*1048576*2, (const char*)Wo  + (size_t)d*1048576*4, wtC, 1024, 1024);
    k_transpose2<<<dim3(128, 32), 256, 0, stream>>>(flag,
        (const char*)W1  + (size_t)d*4194304*2, (const char*)W1  + (size_t)d*4194304*4, wt1, 1024, 4096);
    k_transpose2<<<dim3(32, 128), 256, 0, stream>>>(flag,
        (const char*)W2  + (size_t)d*4194304*2, (const char*)W2  + (size_t)d*4194304*4, wt2, 4096, 1024);
    k_rot_t<<<1, 256, 0, stream>>>(pROT + (size_t)d * 16384, rtT);

    k_ln<<<8192, 256, 0, stream>>>(x2, pLN1G + d*1024, pLN1B + d*1024, xbf);
    k_gemm<<<dim3(8, 64), 256, 0, stream>>>(xbf, wtA, nullptr, qk, nullptr, 8192, 1024, 1024, 0);
    k_gemm<<<dim3(8, 64), 256, 0, stream>>>(xbf, wtB, nullptr, nullptr, vbb, 8192, 1024, 1024, 3);
    k_bucket_mfma<<<dim3(64, 16), 256, 0, stream>>>(qk, rtT, bkt);
    k_sort<<<64, 256, 0, stream>>>(bkt, stb);
    k_attn<<<4096, 256, 0, stream>>>(qk, vbb, stb, orb, lse);
    k_combine<<<32768, 256, 0, stream>>>(orb, lse, xbf);
    k_gemm<<<dim3(8, 64), 256, 0, stream>>>(xbf, wtC, pBO + d*1024, x1, nullptr, 8192, 1024, 1024, 1);
    k_ln<<<8192, 256, 0, stream>>>(x1, pLN2G + d*1024, pLN2B + d*1024, xbf);
    k_gemm<<<dim3(32, 64), 256, 0, stream>>>(xbf, wt1, pB1 + d*4096, nullptr, orb, 8192, 4096, 1024, 2);
    k_gemm<<<dim3(8, 64), 256, 0, stream>>>(orb, wt2, pB2 + d*1024, x2, nullptr, 8192, 1024, 4096, 1);
  }
  k_final_any<<<8192, 256, 0, stream>>>(flag, x1, x2, d_out);
}

// Round 6
// 1347.409 us; speedup vs baseline: 1.3452x; 1.0677x over previous
//
#include <hip/hip_runtime.h>
#include <hip/hip_bf16.h>
#include <cmath>

using bf16 = __hip_bfloat16;
typedef __attribute__((ext_vector_type(8))) short short8;
typedef __attribute__((ext_vector_type(4))) float floatx4;

__device__ __forceinline__ float bu2f(ushort u) { return __uint_as_float((unsigned)u << 16); }
__device__ __forceinline__ ushort f2bu(float f) {
  union { bf16 b; ushort u; } cv; cv.b = __float2bfloat16(f); return cv.u;
}
__device__ __forceinline__ void gl_lds16(const ushort* g, ushort* l) {
  __builtin_amdgcn_global_load_lds((const __attribute__((address_space(1))) unsigned*)g,
                                   (__attribute__((address_space(3))) unsigned*)l, 16, 0, 0);
}
// tanh-form GELU via hw exp; |err vs erf-GELU| ~2e-4, below bf16 output quantization
__device__ __forceinline__ float fast_gelu(float x) {
  float z = 0.7978845608028654f * (x + 0.044715f * x * x * x);
  z = fmaxf(fminf(z, 10.f), -10.f);
  float e = __expf(2.f * z);
  float t = (e - 1.f) / (e + 1.f);
  return 0.5f * x * (1.f + t);
}

static constexpr int kT   = 4096;
static constexpr int kDim = 1024;
static constexpr float kScale   = 0.08838834764831845f;  // 1/sqrt(128)
static constexpr float kSelfVal = -5.0e4f;

// ---------------- dtype detector: bf16 vs fp32 inputs ----------------
__device__ __forceinline__ int sane_v(float f) { float a = fabsf(f); return (a > 1e-4f && a < 1e4f) ? 1 : 0; }

__global__ __launch_bounds__(256) void k_detect(const unsigned* __restrict__ x, int* __restrict__ flag) {
  __shared__ int cnt;
  int tid = threadIdx.x;
  if (tid == 0) cnt = 0;
  __syncthreads();
  int my = 0;
  const uint4* p = (const uint4*)x;
  for (int q = 0; q < 16; q++) {
    uint4 u = p[tid * 16 + q];
    my += sane_v(__uint_as_float(u.x << 16)) + sane_v(__uint_as_float(u.x & 0xffff0000u));
    my += sane_v(__uint_as_float(u.y << 16)) + sane_v(__uint_as_float(u.y & 0xffff0000u));
    my += sane_v(__uint_as_float(u.z << 16)) + sane_v(__uint_as_float(u.z & 0xffff0000u));
    my += sane_v(__uint_as_float(u.w << 16)) + sane_v(__uint_as_float(u.w & 0xffff0000u));
  }
  atomicAdd(&cnt, my);
  __syncthreads();
  if (tid == 0) flag[0] = (cnt >= 24576) ? 1 : 0;
}

__global__ __launch_bounds__(256) void k_cvt(const int* __restrict__ flag, const void* __restrict__ src,
                                             ushort* __restrict__ dst, int n) {
  int i = blockIdx.x * 256 + threadIdx.x;
  if (i >= n) return;
  dst[i] = (*flag) ? ((const ushort*)src)[i] : f2bu(((const float*)src)[i]);
}

__global__ __launch_bounds__(256) void k_init_any(const int* __restrict__ flag, const void* __restrict__ x,
                                                  float* __restrict__ x1, float* __restrict__ x2) {
  int i = blockIdx.x * 1024 + threadIdx.x * 4;
  float4 f;
  if (*flag) {
    ushort4 u = *(const ushort4*)((const ushort*)x + i);
    f.x = bu2f(u.x); f.y = bu2f(u.y); f.z = bu2f(u.z); f.w = bu2f(u.w);
  } else {
    f = *(const float4*)((const float*)x + i);
  }
  *(float4*)(x1 + i) = f;
  *(float4*)(x2 + i) = f;
}

__global__ __launch_bounds__(256) void k_final_any(const int* __restrict__ flag, const float* __restrict__ x1,
                                                   const float* __restrict__ x2, void* __restrict__ out) {
  int i = blockIdx.x * 1024 + threadIdx.x * 4;
  float4 a = *(const float4*)(x1 + i);
  float4 b = *(const float4*)(x2 + i);
  float4 s; s.x = a.x + b.x; s.y = a.y + b.y; s.z = a.z + b.z; s.w = a.w + b.w;
  if (*flag) {
    ushort4 u; u.x = f2bu(s.x); u.y = f2bu(s.y); u.z = f2bu(s.z); u.w = f2bu(s.w);
    *(ushort4*)((ushort*)out + i) = u;
  } else {
    *(float4*)((float*)out + i) = s;
  }
}

// ---------------- layernorm: fp32 in -> bf16 out ----------------
__global__ __launch_bounds__(256) void k_ln(const float* __restrict__ x, const ushort* __restrict__ g,
                                            const ushort* __restrict__ be, ushort* __restrict__ out) {
  __shared__ float ws[4], ws2[4];
  int row = blockIdx.x, tid = threadIdx.x;
  const float* xr = x + (size_t)row * kDim + tid * 4;
  float4 v = *(const float4*)xr;
  float s  = v.x + v.y + v.z + v.w;
  float s2 = v.x*v.x + v.y*v.y + v.z*v.z + v.w*v.w;
  #pragma unroll
  for (int off = 32; off; off >>= 1) { s += __shfl_down(s, off); s2 += __shfl_down(s2, off); }
  int wave = tid >> 6, lane = tid & 63;
  if (lane == 0) { ws[wave] = s; ws2[wave] = s2; }
  __syncthreads();
  s  = ws[0] + ws[1] + ws[2] + ws[3];
  s2 = ws2[0] + ws2[1] + ws2[2] + ws2[3];
  float mean = s * (1.f/1024.f);
  float var  = fmaxf(s2 * (1.f/1024.f) - mean*mean, 0.f);
  float rstd = rsqrtf(var + 1e-5f);
  int cb = tid * 4;
  ushort* o = out + (size_t)row * kDim + cb;
  o[0] = f2bu((v.x - mean) * rstd * bu2f(g[cb+0]) + bu2f(be[cb+0]));
  o[1] = f2bu((v.y - mean) * rstd * bu2f(g[cb+1]) + bu2f(be[cb+1]));
  o[2] = f2bu((v.z - mean) * rstd * bu2f(g[cb+2]) + bu2f(be[cb+2]));
  o[3] = f2bu((v.w - mean) * rstd * bu2f(g[cb+3]) + bu2f(be[cb+3]));
}

// ---------------- dual-dtype weight transpose: in[K,N] -> out[N,K] ----------------
__global__ __launch_bounds__(256) void k_transpose2(const int* __restrict__ flag, const void* __restrict__ src_bf,
                                                    const void* __restrict__ src_f, ushort* __restrict__ out,
                                                    int K, int N) {
  __shared__ ushort tile[32][33];
  int isbf = *flag;
  int nb = blockIdx.x * 32, kb = blockIdx.y * 32;
  int tx = threadIdx.x & 31, ty = threadIdx.x >> 5;
  for (int r = ty; r < 32; r += 8) {
    size_t idx = (size_t)(kb + r) * N + nb + tx;
    tile[r][tx] = isbf ? ((const ushort*)src_bf)[idx] : f2bu(((const float*)src_f)[idx]);
  }
  __syncthreads();
  for (int r = ty; r < 32; r += 8) out[(size_t)(nb + r) * K + kb + tx] = tile[tx][r];
}

// ---------------- rot transpose: rot[k=128][n=128] -> rotT[n=128][k=128] ----------------
__global__ __launch_bounds__(256) void k_rot_t(const ushort* __restrict__ rot, ushort* __restrict__ rotT) {
  int tid = threadIdx.x;
  for (int idx = tid; idx < 16384; idx += 256) {
    int n = idx >> 7, k = idx & 127;
    rotT[idx] = rot[k * 128 + n];
  }
}

// ---------------- GEMM with global_load_lds staging ----------------
// mode 0: Cf = A@B            mode 1: Cf += A@B + bias
// mode 2: Cb = bf16(gelu(A@B+bias))  mode 3: Cb = bf16(A@B)
// mode 5: split-precision out: Cb = hi(A@B), Cb2 = lo(A@B)
__global__ __launch_bounds__(256) void k_gemm(const ushort* __restrict__ A, const ushort* __restrict__ Bt,
                                              const ushort* __restrict__ bias, float* __restrict__ Cf,
                                              ushort* __restrict__ Cb, ushort* __restrict__ Cb2,
                                              int M, int N, int K, int mode) {
  __shared__ alignas(16) ushort As[128*32];
  __shared__ alignas(16) ushort Bs[128*32];
  const int tid = threadIdx.x;
  const int lane = tid & 63, wave = tid >> 6;
  const int m0 = blockIdx.y * 128, n0 = blockIdx.x * 128;
  const int wm = (wave & 1) * 64, wn = (wave >> 1) * 64;
  const int lr = lane & 15, lk = (lane >> 4) * 8;
  const int row = tid >> 2, c8 = (tid & 3) * 8;
  floatx4 acc[4][4];
  #pragma unroll
  for (int mi = 0; mi < 4; mi++)
    #pragma unroll
    for (int ni = 0; ni < 4; ni++) acc[mi][ni] = (floatx4){0.f, 0.f, 0.f, 0.f};

  const ushort* Ab = A  + (size_t)(m0 + row) * K + c8;
  const ushort* Ab2= A  + (size_t)(m0 + row + 64) * K + c8;
  const ushort* Bb = Bt + (size_t)(n0 + row) * K + c8;
  const ushort* Bb2= Bt + (size_t)(n0 + row + 64) * K + c8;
  ushort* lA0 = As + wave*512;
  ushort* lA1 = As + 2048 + wave*512;
  ushort* lB0 = Bs + wave*512;
  ushort* lB1 = Bs + 2048 + wave*512;

  for (int k0 = 0; k0 < K; k0 += 32) {
    __syncthreads();
    gl_lds16(Ab  + k0, lA0);
    gl_lds16(Ab2 + k0, lA1);
    gl_lds16(Bb  + k0, lB0);
    gl_lds16(Bb2 + k0, lB1);
    __syncthreads();
    short8 a[4], b[4];
    #pragma unroll
    for (int mi = 0; mi < 4; mi++) a[mi] = *(const short8*)&As[(wm + mi*16 + lr)*32 + lk];
    #pragma unroll
    for (int ni = 0; ni < 4; ni++) b[ni] = *(const short8*)&Bs[(wn + ni*16 + lr)*32 + lk];
    #pragma unroll
    for (int mi = 0; mi < 4; mi++)
      #pragma unroll
      for (int ni = 0; ni < 4; ni++)
        acc[mi][ni] = __builtin_amdgcn_mfma_f32_16x16x32_bf16(a[mi], b[ni], acc[mi][ni], 0, 0, 0);
  }
  #pragma unroll
  for (int mi = 0; mi < 4; mi++) {
    #pragma unroll
    for (int ni = 0; ni < 4; ni++) {
      int col = n0 + wn + ni*16 + lr;
      float bv = (mode == 1 || mode == 2) ? bu2f(bias[col]) : 0.f;
      #pragma unroll
      for (int q = 0; q < 4; q++) {
        int r2 = m0 + wm + mi*16 + (lane >> 4)*4 + q;
        float val = acc[mi][ni][q];
        if (mode == 0) {
          Cf[(size_t)r2 * N + col] = val;
        } else if (mode == 1) {
          Cf[(size_t)r2 * N + col] += val + bv;
        } else if (mode == 2) {
          Cb[(size_t)r2 * N + col] = f2bu(fast_gelu(val + bv));
        } else if (mode == 3) {
          Cb[(size_t)r2 * N + col] = f2bu(val);
        } else {
          ushort h = f2bu(val);
          Cb [(size_t)r2 * N + col] = h;
          Cb2[(size_t)r2 * N + col] = f2bu(val - bu2f(h));
        }
      }
    }
  }
}

// ---------------- MFMA bucket: consumes qk hi/lo bf16 planes; in-register first-max argmax ----------------
__global__ __launch_bounds__(256) void k_bucket_mfma(const ushort* __restrict__ qkh, const ushort* __restrict__ qkl,
                                                     const ushort* __restrict__ rotT, int* __restrict__ bkt) {
  __shared__ alignas(16) ushort Bs[128*128];  // rotT [n][k]  32 KB
  __shared__ alignas(16) ushort Ah[64*128];   // Q hi         16 KB
  __shared__ alignas(16) ushort Al[64*128];   // Q lo         16 KB
  const int tid = threadIdx.x;
  const int lane = tid & 63, wave = tid >> 6;
  const int lr = lane & 15, lk = (lane >> 4) * 8;
  const int tt = blockIdx.x * 64;
  const int bh = blockIdx.y;
  const int b = bh >> 3, hh = bh & 7;

  {
    int r = tid >> 2, c0 = (tid & 3) * 32;
    size_t base = ((size_t)(b * kT + tt + r)) * kDim + hh * 128 + c0;
    const uint4* sh = (const uint4*)(qkh + base);
    const uint4* sl = (const uint4*)(qkl + base);
    uint4* dh = (uint4*)&Ah[r * 128 + c0];
    uint4* dl = (uint4*)&Al[r * 128 + c0];
    #pragma unroll
    for (int i = 0; i < 4; i++) { dh[i] = sh[i]; dl[i] = sl[i]; }
  }
  {
    const uint4* src = (const uint4*)rotT;
    uint4* dst = (uint4*)Bs;
    for (int i = tid; i < 2048; i += 256) dst[i] = src[i];
  }
  __syncthreads();

  floatx4 acc[4][2];
  #pragma unroll
  for (int mi = 0; mi < 4; mi++) { acc[mi][0] = (floatx4){0,0,0,0}; acc[mi][1] = (floatx4){0,0,0,0}; }
  #pragma unroll
  for (int ks = 0; ks < 4; ks++) {
    short8 a[4], bb[2];
    #pragma unroll
    for (int ni = 0; ni < 2; ni++) bb[ni] = *(const short8*)&Bs[(wave*32 + ni*16 + lr)*128 + ks*32 + lk];
    #pragma unroll
    for (int mi = 0; mi < 4; mi++) a[mi] = *(const short8*)&Ah[(mi*16 + lr)*128 + ks*32 + lk];
    #pragma unroll
    for (int mi = 0; mi < 4; mi++)
      #pragma unroll
      for (int ni = 0; ni < 2; ni++)
        acc[mi][ni] = __builtin_amdgcn_mfma_f32_16x16x32_bf16(a[mi], bb[ni], acc[mi][ni], 0, 0, 0);
  }
  #pragma unroll
  for (int ks = 0; ks < 4; ks++) {
    short8 a[4], bb[2];
    #pragma unroll
    for (int ni = 0; ni < 2; ni++) bb[ni] = *(const short8*)&Bs[(wave*32 + ni*16 + lr)*128 + ks*32 + lk];
    #pragma unroll
    for (int mi = 0; mi < 4; mi++) a[mi] = *(const short8*)&Al[(mi*16 + lr)*128 + ks*32 + lk];
    #pragma unroll
    for (int mi = 0; mi < 4; mi++)
      #pragma unroll
      for (int ni = 0; ni < 2; ni++)
        acc[mi][ni] = __builtin_amdgcn_mfma_f32_16x16x32_bf16(a[mi], bb[ni], acc[mi][ni], 0, 0, 0);
  }

  #pragma unroll
  for (int mi = 0; mi < 4; mi++) {
    #pragma unroll
    for (int q = 0; q < 4; q++) {
      float v0 = acc[mi][0][q];
      float v1 = acc[mi][1][q];
      float best = v0; int bidx = lr;
      if (v1  > best) { best = v1;  bidx = 16 + lr; }
      if (-v0 > best) { best = -v0; bidx = 32 + lr; }
      if (-v1 > best) { best = -v1; bidx = 48 + lr; }
      #pragma unroll
      for (int m = 1; m <= 8; m <<= 1) {
        float ov = __shfl_xor(best, m);
        int   oi = __shfl_xor(bidx, m);
        if (ov > best || (ov == best && oi < bidx)) { best = ov; bidx = oi; }
      }
      if (lr == 0) {
        int row = mi*16 + ((lane >> 4) & 3)*4 + q;
        bkt[(bh*4 + wave)*4096 + tt + row] = bidx;
      }
    }
  }
}

// ---------------- stable counting sort per (bh,hash) ----------------
__global__ __launch_bounds__(256) void k_sort(const int* __restrict__ bkt, int* __restrict__ st) {
  __shared__ unsigned char  hist[64*256];
  __shared__ unsigned short offs[64*256];
  __shared__ int base[64];
  int tid = threadIdx.x, grp = blockIdx.x;
  const int* bk = bkt + grp * 4096;
  for (int i = tid; i < 64*256; i += 256) hist[i] = 0;
  __syncthreads();
  int myb[16];
  #pragma unroll
  for (int j = 0; j < 16; j++) {
    myb[j] = bk[tid*16 + j];
    hist[myb[j]*256 + tid] += 1;
  }
  __syncthreads();
  if (tid < 64) {
    int run = 0;
    for (int t = 0; t < 256; t++) { offs[tid*256 + t] = (unsigned short)run; run += hist[tid*256 + t]; }
    base[tid] = run;
  }
  __syncthreads();
  if (tid == 0) {
    int run = 0;
    for (int b2 = 0; b2 < 64; b2++) { int c = base[b2]; base[b2] = run; run += c; }
  }
  __syncthreads();
  #pragma unroll
  for (int j = 0; j < 16; j++) {
    int b2 = myb[j];
    int r = 0;
    for (int jj = 0; jj < j; jj++) r += (myb[jj] == b2) ? 1 : 0;
    st[grp*4096 + base[b2] + (int)offs[b2*256 + tid] + r] = tid*16 + j;
  }
}

// ---------------- chunked LSH attention (bf16 qk hi-plane input) ----------------
__global__ __launch_bounds__(256) void k_attn(const ushort* __restrict__ qkh, const ushort* __restrict__ vbuf,
                                              const int* __restrict__ st, ushort* __restrict__ o_r,
                                              float* __restrict__ lse_r) {
  __shared__ alignas(16) ushort KV[128*136];
  __shared__ alignas(16) ushort Ps[64*136];
  __shared__ float rnorm[128];
  __shared__ int   kposs[128];
  __shared__ float red1[64*4];
  __shared__ float red2[64*4];
  __shared__ float lrow[64];

  const int tid = threadIdx.x;
  const int bid = blockIdx.x;
  const int bh = bid >> 8;
  const int c  = bid & 255;
  const int h  = c >> 6;
  const int cprev = (c + 255) & 255;
  const int b  = bh >> 3, hh = bh & 7;
  const int lane = tid & 63, wave = tid >> 6;
  const int lr = lane & 15, lk = (lane >> 4) * 8;

  {
    int j = tid >> 1, half = tid & 1;
    int slot = (j < 64) ? (c*64 + j) : (cprev*64 + (j - 64));
    int pos = st[bh*16384 + slot];
    if (half == 0) kposs[j] = pos;
    const ushort* src = qkh + ((size_t)(b * kT + pos)) * kDim + hh*128 + half*64;
    float ss = 0.f;
    #pragma unroll
    for (int i2 = 0; i2 < 64; i2 += 8) {
      uint4 u = *(const uint4*)(src + i2);
      *(uint4*)&KV[j*136 + half*64 + i2] = u;
      float f0 = bu2f((ushort)(u.x & 0xffffu)), f1 = bu2f((ushort)(u.x >> 16));
      float f2 = bu2f((ushort)(u.y & 0xffffu)), f3 = bu2f((ushort)(u.y >> 16));
      float f4 = bu2f((ushort)(u.z & 0xffffu)), f5 = bu2f((ushort)(u.z >> 16));
      float f6 = bu2f((ushort)(u.w & 0xffffu)), f7 = bu2f((ushort)(u.w >> 16));
      ss += f0*f0 + f1*f1 + f2*f2 + f3*f3 + f4*f4 + f5*f5 + f6*f6 + f7*f7;
    }
    ss += __shfl_xor(ss, 1);
    if (half == 0) rnorm[j] = 1.f / fmaxf(sqrtf(ss), 1e-12f);
  }
  __syncthreads();

  {
    floatx4 acc[4][2];
    #pragma unroll
    for (int mi = 0; mi < 4; mi++) { acc[mi][0] = (floatx4){0,0,0,0}; acc[mi][1] = (floatx4){0,0,0,0}; }
    #pragma unroll
    for (int ks = 0; ks < 4; ks++) {
      short8 a[4], bb[2];
      #pragma unroll
      for (int mi = 0; mi < 4; mi++) a[mi]  = *(const short8*)&KV[(mi*16 + lr)*136 + ks*32 + lk];
      #pragma unroll
      for (int ni = 0; ni < 2; ni++) bb[ni] = *(const short8*)&KV[(wave*32 + ni*16 + lr)*136 + ks*32 + lk];
      #pragma unroll
      for (int mi = 0; mi < 4; mi++)
        #pragma unroll
        for (int ni = 0; ni < 2; ni++)
          acc[mi][ni] = __builtin_amdgcn_mfma_f32_16x16x32_bf16(a[mi], bb[ni], acc[mi][ni], 0, 0, 0);
    }
    #pragma unroll
    for (int mi = 0; mi < 4; mi++) {
      #pragma unroll
      for (int ni = 0; ni < 2; ni++) {
        int col = wave*32 + ni*16 + lr;
        float rn = rnorm[col] * kScale;
        int cpos = kposs[col];
        #pragma unroll
        for (int q = 0; q < 4; q++) {
          int row = mi*16 + (lane >> 4)*4 + q;
          float val = acc[mi][ni][q] * rn;
          if (cpos == kposs[row]) val = kSelfVal;
          Ps[row*136 + col] = f2bu(val);
        }
      }
    }
  }
  __syncthreads();

  {
    int j = tid >> 1, half = tid & 1;
    int pos = kposs[j];
    const ushort* src = vbuf + ((size_t)(b * kT + pos)) * kDim + hh*128 + half*64;
    #pragma unroll
    for (int i2 = 0; i2 < 64; i2 += 8) {
      uint4 u = *(const uint4*)(src + i2);
      int d0 = half*64 + i2;
      KV[(d0+0)*136 + j] = (ushort)(u.x & 0xffffu); KV[(d0+1)*136 + j] = (ushort)(u.x >> 16);
      KV[(d0+2)*136 + j] = (ushort)(u.y & 0xffffu); KV[(d0+3)*136 + j] = (ushort)(u.y >> 16);
      KV[(d0+4)*136 + j] = (ushort)(u.z & 0xffffu); KV[(d0+5)*136 + j] = (ushort)(u.z >> 16);
      KV[(d0+6)*136 + j] = (ushort)(u.w & 0xffffu); KV[(d0+7)*136 + j] = (ushort)(u.w >> 16);
    }
  }

  {
    int i = tid >> 2, part = tid & 3;
    const int jb = part * 32;
    float m = -1e30f;
    for (int j2 = 0; j2 < 32; j2++) m = fmaxf(m, bu2f(Ps[i*136 + jb + j2]));
    red1[i*4 + part] = m;
    __syncthreads();
    m = fmaxf(fmaxf(red1[i*4+0], red1[i*4+1]), fmaxf(red1[i*4+2], red1[i*4+3]));
    float ssum = 0.f;
    for (int j2 = 0; j2 < 32; j2++) {
      float arg = fmaxf(fminf(bu2f(Ps[i*136 + jb + j2]) - m, 0.f), -80.f);
      float p = __expf(arg);
      ssum += p;
      Ps[i*136 + jb + j2] = f2bu(p);
    }
    red2[i*4 + part] = ssum;
    __syncthreads();
    if (part == 0) {
      float l = fmaxf(red2[i*4+0] + red2[i*4+1] + red2[i*4+2] + red2[i*4+3], 1e-20f);
      lrow[i] = 1.f / l;
      lse_r[(size_t)(bh*4 + h)*4096 + kposs[i]] = m + __logf(l);
    }
  }
  __syncthreads();

  {
    floatx4 acc[4][2];
    #pragma unroll
    for (int mi = 0; mi < 4; mi++) { acc[mi][0] = (floatx4){0,0,0,0}; acc[mi][1] = (floatx4){0,0,0,0}; }
    #pragma unroll
    for (int ks = 0; ks < 4; ks++) {
      short8 a[4], bb[2];
      #pragma unroll
      for (int mi = 0; mi < 4; mi++) a[mi]  = *(const short8*)&Ps[(mi*16 + lr)*136 + ks*32 + lk];
      #pragma unroll
      for (int ni = 0; ni < 2; ni++) bb[ni] = *(const short8*)&KV[(wave*32 + ni*16 + lr)*136 + ks*32 + lk];
      #pragma unroll
      for (int mi = 0; mi < 4; mi++)
        #pragma unroll
        for (int ni = 0; ni < 2; ni++)
          acc[mi][ni] = __builtin_amdgcn_mfma_f32_16x16x32_bf16(a[mi], bb[ni], acc[mi][ni], 0, 0, 0);
    }
    #pragma unroll
    for (int mi = 0; mi < 4; mi++) {
      #pragma unroll
      for (int ni = 0; ni < 2; ni++) {
        int d = wave*32 + ni*16 + lr;
        #pragma unroll
        for (int q = 0; q < 4; q++) {
          int row = mi*16 + (lane >> 4)*4 + q;
          float o = acc[mi][ni][q] * lrow[row];
          o_r[((size_t)(bh*4 + h)*4096 + kposs[row])*128 + d] = f2bu(o);
        }
      }
    }
  }
}

// ---------------- combine hash rounds ----------------
__global__ __launch_bounds__(256) void k_combine(const ushort* __restrict__ o_r, const float* __restrict__ lse_r,
                                                 ushort* __restrict__ attnbf) {
  int rid = blockIdx.x * 2 + (threadIdx.x >> 7);
  int d = threadIdx.x & 127;
  int bh = rid >> 12, t = rid & 4095;
  int b = bh >> 3, hh = bh & 7;
  size_t base = (size_t)bh * 16384 + t;
  float l0 = lse_r[base], l1 = lse_r[base + 4096], l2 = lse_r[base + 8192], l3 = lse_r[base + 12288];
  float M = fmaxf(fmaxf(l0, l1), fmaxf(l2, l3));
  float e0 = __expf(fmaxf(fminf(l0 - M, 0.f), -80.f));
  float e1 = __expf(fmaxf(fminf(l1 - M, 0.f), -80.f));
  float e2 = __expf(fmaxf(fminf(l2 - M, 0.f), -80.f));
  float e3 = __expf(fmaxf(fminf(l3 - M, 0.f), -80.f));
  float inv = 1.f / (e0 + e1 + e2 + e3);
  float o = e0 * bu2f(o_r[(base         )*128 + d]) + e1 * bu2f(o_r[(base +  4096)*128 + d])
          + e2 * bu2f(o_r[(base +  8192)*128 + d]) + e3 * bu2f(o_r[(base + 12288)*128 + d]);
  attnbf[((size_t)b * kT + t) * kDim + hh*128 + d] = f2bu(o * inv);
}

extern "C" void kernel_launch(void* const* d_in, const int* in_sizes, int n_in,
                              void* d_out, int out_size, void* d_ws, size_t ws_size,
                              hipStream_t stream) {
  (void)in_sizes; (void)n_in; (void)out_size; (void)ws_size;
  const void* x     = d_in[0];
  const void* ln1_g = d_in[1];
  const void* ln1_b = d_in[2];
  const void* Wqk   = d_in[3];
  const void* Wv    = d_in[4];
  const void* Wo    = d_in[5];
  const void* bo    = d_in[6];
  const void* ln2_g = d_in[7];
  const void* ln2_b = d_in[8];
  const void* W1    = d_in[9];
  const void* b1    = d_in[10];
  const void* W2    = d_in[11];
  const void* b2    = d_in[12];
  const void* rot   = d_in[13];

  char* w = (char*)d_ws;
  int*    flag = (int*)w;    w += 256;
  ushort* prm  = (ushort*)w; w += 131072;
  float* x1  = (float*)w;  w += 33554432;
  float* x2  = (float*)w;  w += 33554432;
  ushort* qkh = (ushort*)w; w += 16777216;
  ushort* qkl = (ushort*)w; w += 16777216;
  ushort* vbb = (ushort*)w; w += 16777216;
  ushort* xbf = (ushort*)w; w += 16777216;
  ushort* orb = (ushort*)w; w += 67108864;
  float* lse = (float*)w;  w += 1048576;
  int*   bkt = (int*)w;    w += 1048576;
  int*   stb = (int*)w;    w += 1048576;
  ushort* wtA = (ushort*)w; w += 2097152;
  ushort* wtB = (ushort*)w; w += 2097152;
  ushort* wtC = (ushort*)w; w += 2097152;
  ushort* wt1 = (ushort*)w; w += 8388608;
  ushort* wt2 = (ushort*)w; w += 8388608;
  ushort* rtT = (ushort*)w; w += 32768;

  ushort* pLN1G = prm + 0;     ushort* pLN1B = prm + 2048;
  ushort* pBO   = prm + 4096;  ushort* pLN2G = prm + 6144;
  ushort* pLN2B = prm + 8192;  ushort* pB1   = prm + 10240;
  ushort* pB2   = prm + 18432; ushort* pROT  = prm + 20480;

  k_detect<<<1, 256, 0, stream>>>((const unsigned*)x, flag);
  k_cvt<<<8,   256, 0, stream>>>(flag, ln1_g, pLN1G, 2048);
  k_cvt<<<8,   256, 0, stream>>>(flag, ln1_b, pLN1B, 2048);
  k_cvt<<<8,   256, 0, stream>>>(flag, bo,    pBO,   2048);
  k_cvt<<<8,   256, 0, stream>>>(flag, ln2_g, pLN2G, 2048);
  k_cvt<<<8,   256, 0, stream>>>(flag, ln2_b, pLN2B, 2048);
  k_cvt<<<32,  256, 0, stream>>>(flag, b1,    pB1,   8192);
  k_cvt<<<8,   256, 0, stream>>>(flag, b2,    pB2,   2048);
  k_cvt<<<128, 256, 0, stream>>>(flag, rot,   pROT,  32768);
  k_init_any<<<8192, 256, 0, stream>>>(flag, x, x1, x2);

  for (int d = 0; d < 2; d++) {
    k_transpose2<<<dim3(32, 32),  256, 0, stream>>>(flag,
        (const char*)Wqk + (size_t)d*1048576*2, (const char*)Wqk + (size_t)d*1048576*4, wtA, 1024, 1024);
    k_transpose2<<<dim3(32, 32),  256, 0, stream>>>(flag,
        (const char*)Wv  + (size_t)d*1048576*2, (const char*)Wv  + (size_t)d*1048576*4, wtB, 1024, 1024);
    k_transpose2<<<dim3(32, 32),  256, 0, stream>>>(flag,
        (const char*)Wo  + (size_t)d*1048576*2, (const char*)Wo  + (size_t)d*1048576*4, wtC, 1024, 1024);
    k_transpose2<<<dim3(128, 32), 256, 0, stream>>>(flag,
        (const char*)W1  + (size_t)d*4194304*2, (const char*)W1  + (size_t)d*4194304*4, wt1, 1024, 4096);
    k_transpose2<<<dim3(32, 128), 256, 0, stream>>>(flag,
        (const char*)W2  + (size_t)d*4194304*2, (const char*)W2  + (size_t)d*4194304*4, wt2, 4096, 1024);
    k_rot_t<<<1, 256, 0, stream>>>(pROT + (size_t)d * 16384, rtT);

    k_ln<<<8192, 256, 0, stream>>>(x2, pLN1G + d*1024, pLN1B + d*1024, xbf);
    k_gemm<<<dim3(8, 64), 256, 0, stream>>>(xbf, wtA, nullptr, nullptr, qkh, qkl, 8192, 1024, 1024, 5);
    k_gemm<<<dim3(8, 64), 256, 0, stream>>>(xbf, wtB, nullptr, nullptr, vbb, nullptr, 8192, 1024, 1024, 3);
    k_bucket_mfma<<<dim3(64, 16), 256, 0, stream>>>(qkh, qkl, rtT, bkt);
    k_sort<<<64, 256, 0, stream>>>(bkt, stb);
    k_attn<<<4096, 256, 0, stream>>>(qkh, vbb, stb, orb, lse);
    k_combine<<<32768, 256, 0, stream>>>(orb, lse, xbf);
    k_gemm<<<dim3(8, 64), 256, 0, stream>>>(xbf, wtC, pBO + d*1024, x1, nullptr, nullptr, 8192, 1024, 1024, 1);
    k_ln<<<8192, 256, 0, stream>>>(x1, pLN2G + d*1024, pLN2B + d*1024, xbf);
    k_gemm<<<dim3(32, 64), 256, 0, stream>>>(xbf, wt1, pB1 + d*4096, nullptr, orb, nullptr, 8192, 4096, 1024, 2);
    k_gemm<<<dim3(8, 64), 256, 0, stream>>>(orb, wt2, pB2 + d*1024, x2, nullptr, nullptr, 8192, 1024, 4096, 1);
  }
  k_final_any<<<8192, 256, 0, stream>>>(flag, x1, x2, d_out);
}

// Round 7
// 1265.612 us; speedup vs baseline: 1.4322x; 1.0646x over previous
//
#include <hip/hip_runtime.h>
#include <hip/hip_bf16.h>
#include <cmath>

using bf16 = __hip_bfloat16;
typedef __attribute__((ext_vector_type(8))) short short8;
typedef __attribute__((ext_vector_type(4))) float floatx4;

__device__ __forceinline__ float bu2f(ushort u) { return __uint_as_float((unsigned)u << 16); }
__device__ __forceinline__ ushort f2bu(float f) {
  union { bf16 b; ushort u; } cv; cv.b = __float2bfloat16(f); return cv.u;
}
__device__ __forceinline__ void gl_lds16(const ushort* g, ushort* l) {
  __builtin_amdgcn_global_load_lds((const __attribute__((address_space(1))) unsigned*)g,
                                   (__attribute__((address_space(3))) unsigned*)l, 16, 0, 0);
}
// tanh-form GELU via hw exp; |err vs erf-GELU| ~2e-4, below bf16 output quantization
__device__ __forceinline__ float fast_gelu(float x) {
  float z = 0.7978845608028654f * (x + 0.044715f * x * x * x);
  z = fmaxf(fminf(z, 10.f), -10.f);
  float e = __expf(2.f * z);
  float t = (e - 1.f) / (e + 1.f);
  return 0.5f * x * (1.f + t);
}

static constexpr int kT   = 4096;
static constexpr int kDim = 1024;
static constexpr float kScale   = 0.08838834764831845f;  // 1/sqrt(128)
static constexpr float kSelfVal = -5.0e4f;

// ---------------- dtype detector: bf16 vs fp32 inputs ----------------
__device__ __forceinline__ int sane_v(float f) { float a = fabsf(f); return (a > 1e-4f && a < 1e4f) ? 1 : 0; }

__global__ __launch_bounds__(256) void k_detect(const unsigned* __restrict__ x, int* __restrict__ flag) {
  __shared__ int cnt;
  int tid = threadIdx.x;
  if (tid == 0) cnt = 0;
  __syncthreads();
  int my = 0;
  const uint4* p = (const uint4*)x;
  for (int q = 0; q < 16; q++) {
    uint4 u = p[tid * 16 + q];
    my += sane_v(__uint_as_float(u.x << 16)) + sane_v(__uint_as_float(u.x & 0xffff0000u));
    my += sane_v(__uint_as_float(u.y << 16)) + sane_v(__uint_as_float(u.y & 0xffff0000u));
    my += sane_v(__uint_as_float(u.z << 16)) + sane_v(__uint_as_float(u.z & 0xffff0000u));
    my += sane_v(__uint_as_float(u.w << 16)) + sane_v(__uint_as_float(u.w & 0xffff0000u));
  }
  atomicAdd(&cnt, my);
  __syncthreads();
  if (tid == 0) flag[0] = (cnt >= 24576) ? 1 : 0;
}

__global__ __launch_bounds__(256) void k_cvt(const int* __restrict__ flag, const void* __restrict__ src,
                                             ushort* __restrict__ dst, int n) {
  int i = blockIdx.x * 256 + threadIdx.x;
  if (i >= n) return;
  dst[i] = (*flag) ? ((const ushort*)src)[i] : f2bu(((const float*)src)[i]);
}

__global__ __launch_bounds__(256) void k_init_any(const int* __restrict__ flag, const void* __restrict__ x,
                                                  float* __restrict__ x1, float* __restrict__ x2) {
  int i = blockIdx.x * 1024 + threadIdx.x * 4;
  float4 f;
  if (*flag) {
    ushort4 u = *(const ushort4*)((const ushort*)x + i);
    f.x = bu2f(u.x); f.y = bu2f(u.y); f.z = bu2f(u.z); f.w = bu2f(u.w);
  } else {
    f = *(const float4*)((const float*)x + i);
  }
  *(float4*)(x1 + i) = f;
  *(float4*)(x2 + i) = f;
}

__global__ __launch_bounds__(256) void k_final_any(const int* __restrict__ flag, const float* __restrict__ x1,
                                                   const float* __restrict__ x2, void* __restrict__ out) {
  int i = blockIdx.x * 1024 + threadIdx.x * 4;
  float4 a = *(const float4*)(x1 + i);
  float4 b = *(const float4*)(x2 + i);
  float4 s; s.x = a.x + b.x; s.y = a.y + b.y; s.z = a.z + b.z; s.w = a.w + b.w;
  if (*flag) {
    ushort4 u; u.x = f2bu(s.x); u.y = f2bu(s.y); u.z = f2bu(s.z); u.w = f2bu(s.w);
    *(ushort4*)((ushort*)out + i) = u;
  } else {
    *(float4*)((float*)out + i) = s;
  }
}

// ---------------- layernorm: fp32 in -> bf16 out ----------------
__global__ __launch_bounds__(256) void k_ln(const float* __restrict__ x, const ushort* __restrict__ g,
                                            const ushort* __restrict__ be, ushort* __restrict__ out) {
  __shared__ float ws[4], ws2[4];
  int row = blockIdx.x, tid = threadIdx.x;
  const float* xr = x + (size_t)row * kDim + tid * 4;
  float4 v = *(const float4*)xr;
  float s  = v.x + v.y + v.z + v.w;
  float s2 = v.x*v.x + v.y*v.y + v.z*v.z + v.w*v.w;
  #pragma unroll
  for (int off = 32; off; off >>= 1) { s += __shfl_down(s, off); s2 += __shfl_down(s2, off); }
  int wave = tid >> 6, lane = tid & 63;
  if (lane == 0) { ws[wave] = s; ws2[wave] = s2; }
  __syncthreads();
  s  = ws[0] + ws[1] + ws[2] + ws[3];
  s2 = ws2[0] + ws2[1] + ws2[2] + ws2[3];
  float mean = s * (1.f/1024.f);
  float var  = fmaxf(s2 * (1.f/1024.f) - mean*mean, 0.f);
  float rstd = rsqrtf(var + 1e-5f);
  int cb = tid * 4;
  ushort* o = out + (size_t)row * kDim + cb;
  o[0] = f2bu((v.x - mean) * rstd * bu2f(g[cb+0]) + bu2f(be[cb+0]));
  o[1] = f2bu((v.y - mean) * rstd * bu2f(g[cb+1]) + bu2f(be[cb+1]));
  o[2] = f2bu((v.z - mean) * rstd * bu2f(g[cb+2]) + bu2f(be[cb+2]));
  o[3] = f2bu((v.w - mean) * rstd * bu2f(g[cb+3]) + bu2f(be[cb+3]));
}

// ---------------- dual-dtype weight transpose: in[K,N] -> out[N,K] ----------------
__global__ __launch_bounds__(256) void k_transpose2(const int* __restrict__ flag, const void* __restrict__ src_bf,
                                                    const void* __restrict__ src_f, ushort* __restrict__ out,
                                                    int K, int N) {
  __shared__ ushort tile[32][33];
  int isbf = *flag;
  int nb = blockIdx.x * 32, kb = blockIdx.y * 32;
  int tx = threadIdx.x & 31, ty = threadIdx.x >> 5;
  for (int r = ty; r < 32; r += 8) {
    size_t idx = (size_t)(kb + r) * N + nb + tx;
    tile[r][tx] = isbf ? ((const ushort*)src_bf)[idx] : f2bu(((const float*)src_f)[idx]);
  }
  __syncthreads();
  for (int r = ty; r < 32; r += 8) out[(size_t)(nb + r) * K + kb + tx] = tile[tx][r];
}

// ---------------- rot transpose: rot[k=128][n=128] -> rotT[n=128][k=128] ----------------
__global__ __launch_bounds__(256) void k_rot_t(const ushort* __restrict__ rot, ushort* __restrict__ rotT) {
  int tid = threadIdx.x;
  for (int idx = tid; idx < 16384; idx += 256) {
    int n = idx >> 7, k = idx & 127;
    rotT[idx] = rot[k * 128 + n];
  }
}

// ---------------- GEMM: BK=64, XOR-swizzled LDS (conflict-free), global_load_lds staging ----------------
// mode 0: Cf = A@B            mode 1: Cf += A@B + bias
// mode 2: Cb = bf16(gelu(A@B+bias))  mode 3: Cb = bf16(A@B)
// mode 5: split-precision out: Cb = hi(A@B), Cb2 = lo(A@B)
__global__ __launch_bounds__(256) void k_gemm(const ushort* __restrict__ A, const ushort* __restrict__ Bt,
                                              const ushort* __restrict__ bias, float* __restrict__ Cf,
                                              ushort* __restrict__ Cb, ushort* __restrict__ Cb2,
                                              int M, int N, int K, int mode) {
  __shared__ alignas(16) ushort As[128*64];   // 16 KB, rows of 64, col XOR-swizzled by row
  __shared__ alignas(16) ushort Bs[128*64];   // 16 KB
  const int tid = threadIdx.x;
  const int lane = tid & 63, wave = tid >> 6;
  const int m0 = blockIdx.y * 128, n0 = blockIdx.x * 128;
  const int wm = (wave & 1) * 64, wn = (wave >> 1) * 64;
  const int lr = lane & 15, lk = (lane >> 4) * 8;
  // staging: thread t covers row r8 (+32*i), cols (t&7)*8; swizzle s=(r8&7)*8 applied to SOURCE col
  const int r8  = tid >> 3;                       // 0..31
  const int cst = ((tid & 7) * 8) ^ ((r8 & 7) * 8);
  // read-side swizzle (row = wm/wn + mi*16 + lr; (row&7) == (lr&7) since other terms are mult of 8)
  const int swz = (lr & 7) * 8;

  floatx4 acc[4][4];
  #pragma unroll
  for (int mi = 0; mi < 4; mi++)
    #pragma unroll
    for (int ni = 0; ni < 4; ni++) acc[mi][ni] = (floatx4){0.f, 0.f, 0.f, 0.f};

  const ushort* Ap = A  + (size_t)(m0 + r8) * K + cst;
  const ushort* Bp = Bt + (size_t)(n0 + r8) * K + cst;
  const size_t rstep = (size_t)32 * K;

  for (int k0 = 0; k0 < K; k0 += 64) {
    __syncthreads();
    #pragma unroll
    for (int i = 0; i < 4; i++) {
      gl_lds16(Ap + i * rstep + k0, As + i*2048 + wave*512);
      gl_lds16(Bp + i * rstep + k0, Bs + i*2048 + wave*512);
    }
    __syncthreads();
    #pragma unroll
    for (int ks = 0; ks < 2; ks++) {
      const int col = (ks*32 + lk) ^ swz;
      short8 a[4], b[4];
      #pragma unroll
      for (int mi = 0; mi < 4; mi++) a[mi] = *(const short8*)&As[(wm + mi*16 + lr)*64 + col];
      #pragma unroll
      for (int ni = 0; ni < 4; ni++) b[ni] = *(const short8*)&Bs[(wn + ni*16 + lr)*64 + col];
      #pragma unroll
      for (int mi = 0; mi < 4; mi++)
        #pragma unroll
        for (int ni = 0; ni < 4; ni++)
          acc[mi][ni] = __builtin_amdgcn_mfma_f32_16x16x32_bf16(a[mi], b[ni], acc[mi][ni], 0, 0, 0);
    }
  }
  #pragma unroll
  for (int mi = 0; mi < 4; mi++) {
    #pragma unroll
    for (int ni = 0; ni < 4; ni++) {
      int col = n0 + wn + ni*16 + lr;
      float bv = (mode == 1 || mode == 2) ? bu2f(bias[col]) : 0.f;
      #pragma unroll
      for (int q = 0; q < 4; q++) {
        int r2 = m0 + wm + mi*16 + (lane >> 4)*4 + q;
        float val = acc[mi][ni][q];
        if (mode == 0) {
          Cf[(size_t)r2 * N + col] = val;
        } else if (mode == 1) {
          Cf[(size_t)r2 * N + col] += val + bv;
        } else if (mode == 2) {
          Cb[(size_t)r2 * N + col] = f2bu(fast_gelu(val + bv));
        } else if (mode == 3) {
          Cb[(size_t)r2 * N + col] = f2bu(val);
        } else {
          ushort h = f2bu(val);
          Cb [(size_t)r2 * N + col] = h;
          Cb2[(size_t)r2 * N + col] = f2bu(val - bu2f(h));
        }
      }
    }
  }
}

// ---------------- MFMA bucket: consumes qk hi/lo bf16 planes; in-register first-max argmax ----------------
__global__ __launch_bounds__(256) void k_bucket_mfma(const ushort* __restrict__ qkh, const ushort* __restrict__ qkl,
                                                     const ushort* __restrict__ rotT, int* __restrict__ bkt) {
  __shared__ alignas(16) ushort Bs[128*128];  // rotT [n][k]  32 KB
  __shared__ alignas(16) ushort Ah[64*128];   // Q hi         16 KB
  __shared__ alignas(16) ushort Al[64*128];   // Q lo         16 KB
  const int tid = threadIdx.x;
  const int lane = tid & 63, wave = tid >> 6;
  const int lr = lane & 15, lk = (lane >> 4) * 8;
  const int tt = blockIdx.x * 64;
  const int bh = blockIdx.y;
  const int b = bh >> 3, hh = bh & 7;

  {
    int r = tid >> 2, c0 = (tid & 3) * 32;
    size_t base = ((size_t)(b * kT + tt + r)) * kDim + hh * 128 + c0;
    const uint4* sh = (const uint4*)(qkh + base);
    const uint4* sl = (const uint4*)(qkl + base);
    uint4* dh = (uint4*)&Ah[r * 128 + c0];
    uint4* dl = (uint4*)&Al[r * 128 + c0];
    #pragma unroll
    for (int i = 0; i < 4; i++) { dh[i] = sh[i]; dl[i] = sl[i]; }
  }
  {
    const uint4* src = (const uint4*)rotT;
    uint4* dst = (uint4*)Bs;
    for (int i = tid; i < 2048; i += 256) dst[i] = src[i];
  }
  __syncthreads();

  floatx4 acc[4][2];
  #pragma unroll
  for (int mi = 0; mi < 4; mi++) { acc[mi][0] = (floatx4){0,0,0,0}; acc[mi][1] = (floatx4){0,0,0,0}; }
  #pragma unroll
  for (int ks = 0; ks < 4; ks++) {
    short8 a[4], bb[2];
    #pragma unroll
    for (int ni = 0; ni < 2; ni++) bb[ni] = *(const short8*)&Bs[(wave*32 + ni*16 + lr)*128 + ks*32 + lk];
    #pragma unroll
    for (int mi = 0; mi < 4; mi++) a[mi] = *(const short8*)&Ah[(mi*16 + lr)*128 + ks*32 + lk];
    #pragma unroll
    for (int mi = 0; mi < 4; mi++)
      #pragma unroll
      for (int ni = 0; ni < 2; ni++)
        acc[mi][ni] = __builtin_amdgcn_mfma_f32_16x16x32_bf16(a[mi], bb[ni], acc[mi][ni], 0, 0, 0);
  }
  #pragma unroll
  for (int ks = 0; ks < 4; ks++) {
    short8 a[4], bb[2];
    #pragma unroll
    for (int ni = 0; ni < 2; ni++) bb[ni] = *(const short8*)&Bs[(wave*32 + ni*16 + lr)*128 + ks*32 + lk];
    #pragma unroll
    for (int mi = 0; mi < 4; mi++) a[mi] = *(const short8*)&Al[(mi*16 + lr)*128 + ks*32 + lk];
    #pragma unroll
    for (int mi = 0; mi < 4; mi++)
      #pragma unroll
      for (int ni = 0; ni < 2; ni++)
        acc[mi][ni] = __builtin_amdgcn_mfma_f32_16x16x32_bf16(a[mi], bb[ni], acc[mi][ni], 0, 0, 0);
  }

  #pragma unroll
  for (int mi = 0; mi < 4; mi++) {
    #pragma unroll
    for (int q = 0; q < 4; q++) {
      float v0 = acc[mi][0][q];
      float v1 = acc[mi][1][q];
      float best = v0; int bidx = lr;
      if (v1  > best) { best = v1;  bidx = 16 + lr; }
      if (-v0 > best) { best = -v0; bidx = 32 + lr; }
      if (-v1 > best) { best = -v1; bidx = 48 + lr; }
      #pragma unroll
      for (int m = 1; m <= 8; m <<= 1) {
        float ov = __shfl_xor(best, m);
        int   oi = __shfl_xor(bidx, m);
        if (ov > best || (ov == best && oi < bidx)) { best = ov; bidx = oi; }
      }
      if (lr == 0) {
        int row = mi*16 + ((lane >> 4) & 3)*4 + q;
        bkt[(bh*4 + wave)*4096 + tt + row] = bidx;
      }
    }
  }
}

// ---------------- stable counting sort per (bh,hash) ----------------
__global__ __launch_bounds__(256) void k_sort(const int* __restrict__ bkt, int* __restrict__ st) {
  __shared__ unsigned char  hist[64*256];
  __shared__ unsigned short offs[64*256];
  __shared__ int base[64];
  int tid = threadIdx.x, grp = blockIdx.x;
  const int* bk = bkt + grp * 4096;
  for (int i = tid; i < 64*256; i += 256) hist[i] = 0;
  __syncthreads();
  int myb[16];
  #pragma unroll
  for (int j = 0; j < 16; j++) {
    myb[j] = bk[tid*16 + j];
    hist[myb[j]*256 + tid] += 1;
  }
  __syncthreads();
  if (tid < 64) {
    int run = 0;
    for (int t = 0; t < 256; t++) { offs[tid*256 + t] = (unsigned short)run; run += hist[tid*256 + t]; }
    base[tid] = run;
  }
  __syncthreads();
  if (tid == 0) {
    int run = 0;
    for (int b2 = 0; b2 < 64; b2++) { int c = base[b2]; base[b2] = run; run += c; }
  }
  __syncthreads();
  #pragma unroll
  for (int j = 0; j < 16; j++) {
    int b2 = myb[j];
    int r = 0;
    for (int jj = 0; jj < j; jj++) r += (myb[jj] == b2) ? 1 : 0;
    st[grp*4096 + base[b2] + (int)offs[b2*256 + tid] + r] = tid*16 + j;
  }
}

// ---------------- chunked LSH attention (bf16 qk hi-plane input) ----------------
__global__ __launch_bounds__(256) void k_attn(const ushort* __restrict__ qkh, const ushort* __restrict__ vbuf,
                                              const int* __restrict__ st, ushort* __restrict__ o_r,
                                              float* __restrict__ lse_r) {
  __shared__ alignas(16) ushort KV[128*136];
  __shared__ alignas(16) ushort Ps[64*136];
  __shared__ float rnorm[128];
  __shared__ int   kposs[128];
  __shared__ float red1[64*4];
  __shared__ float red2[64*4];
  __shared__ float lrow[64];

  const int tid = threadIdx.x;
  const int bid = blockIdx.x;
  const int bh = bid >> 8;
  const int c  = bid & 255;
  const int h  = c >> 6;
  const int cprev = (c + 255) & 255;
  const int b  = bh >> 3, hh = bh & 7;
  const int lane = tid & 63, wave = tid >> 6;
  const int lr = lane & 15, lk = (lane >> 4) * 8;

  {
    int j = tid >> 1, half = tid & 1;
    int slot = (j < 64) ? (c*64 + j) : (cprev*64 + (j - 64));
    int pos = st[bh*16384 + slot];
    if (half == 0) kposs[j] = pos;
    const ushort* src = qkh + ((size_t)(b * kT + pos)) * kDim + hh*128 + half*64;
    float ss = 0.f;
    #pragma unroll
    for (int i2 = 0; i2 < 64; i2 += 8) {
      uint4 u = *(const uint4*)(src + i2);
      *(uint4*)&KV[j*136 + half*64 + i2] = u;
      float f0 = bu2f((ushort)(u.x & 0xffffu)), f1 = bu2f((ushort)(u.x >> 16));
      float f2 = bu2f((ushort)(u.y & 0xffffu)), f3 = bu2f((ushort)(u.y >> 16));
      float f4 = bu2f((ushort)(u.z & 0xffffu)), f5 = bu2f((ushort)(u.z >> 16));
      float f6 = bu2f((ushort)(u.w & 0xffffu)), f7 = bu2f((ushort)(u.w >> 16));
      ss += f0*f0 + f1*f1 + f2*f2 + f3*f3 + f4*f4 + f5*f5 + f6*f6 + f7*f7;
    }
    ss += __shfl_xor(ss, 1);
    if (half == 0) rnorm[j] = 1.f / fmaxf(sqrtf(ss), 1e-12f);
  }
  __syncthreads();

  {
    floatx4 acc[4][2];
    #pragma unroll
    for (int mi = 0; mi < 4; mi++) { acc[mi][0] = (floatx4){0,0,0,0}; acc[mi][1] = (floatx4){0,0,0,0}; }
    #pragma unroll
    for (int ks = 0; ks < 4; ks++) {
      short8 a[4], bb[2];
      #pragma unroll
      for (int mi = 0; mi < 4; mi++) a[mi]  = *(const short8*)&KV[(mi*16 + lr)*136 + ks*32 + lk];
      #pragma unroll
      for (int ni = 0; ni < 2; ni++) bb[ni] = *(const short8*)&KV[(wave*32 + ni*16 + lr)*136 + ks*32 + lk];
      #pragma unroll
      for (int mi = 0; mi < 4; mi++)
        #pragma unroll
        for (int ni = 0; ni < 2; ni++)
          acc[mi][ni] = __builtin_amdgcn_mfma_f32_16x16x32_bf16(a[mi], bb[ni], acc[mi][ni], 0, 0, 0);
    }
    #pragma unroll
    for (int mi = 0; mi < 4; mi++) {
      #pragma unroll
      for (int ni = 0; ni < 2; ni++) {
        int col = wave*32 + ni*16 + lr;
        float rn = rnorm[col] * kScale;
        int cpos = kposs[col];
        #pragma unroll
        for (int q = 0; q < 4; q++) {
          int row = mi*16 + (lane >> 4)*4 + q;
          float val = acc[mi][ni][q] * rn;
          if (cpos == kposs[row]) val = kSelfVal;
          Ps[row*136 + col] = f2bu(val);
        }
      }
    }
  }
  __syncthreads();

  {
    int j = tid >> 1, half = tid & 1;
    int pos = kposs[j];
    const ushort* src = vbuf + ((size_t)(b * kT + pos)) * kDim + hh*128 + half*64;
    #pragma unroll
    for (int i2 = 0; i2 < 64; i2 += 8) {
      uint4 u = *(const uint4*)(src + i2);
      int d0 = half*64 + i2;
      KV[(d0+0)*136 + j] = (ushort)(u.x & 0xffffu); KV[(d0+1)*136 + j] = (ushort)(u.x >> 16);
      KV[(d0+2)*136 + j] = (ushort)(u.y & 0xffffu); KV[(d0+3)*136 + j] = (ushort)(u.y >> 16);
      KV[(d0+4)*136 + j] = (ushort)(u.z & 0xffffu); KV[(d0+5)*136 + j] = (ushort)(u.z >> 16);
      KV[(d0+6)*136 + j] = (ushort)(u.w & 0xffffu); KV[(d0+7)*136 + j] = (ushort)(u.w >> 16);
    }
  }

  {
    int i = tid >> 2, part = tid & 3;
    const int jb = part * 32;
    float m = -1e30f;
    for (int j2 = 0; j2 < 32; j2++) m = fmaxf(m, bu2f(Ps[i*136 + jb + j2]));
    red1[i*4 + part] = m;
    __syncthreads();
    m = fmaxf(fmaxf(red1[i*4+0], red1[i*4+1]), fmaxf(red1[i*4+2], red1[i*4+3]));
    float ssum = 0.f;
    for (int j2 = 0; j2 < 32; j2++) {
      float arg = fmaxf(fminf(bu2f(Ps[i*136 + jb + j2]) - m, 0.f), -80.f);
      float p = __expf(arg);
      ssum += p;
      Ps[i*136 + jb + j2] = f2bu(p);
    }
    red2[i*4 + part] = ssum;
    __syncthreads();
    if (part == 0) {
      float l = fmaxf(red2[i*4+0] + red2[i*4+1] + red2[i*4+2] + red2[i*4+3], 1e-20f);
      lrow[i] = 1.f / l;
      lse_r[(size_t)(bh*4 + h)*4096 + kposs[i]] = m + __logf(l);
    }
  }
  __syncthreads();

  {
    floatx4 acc[4][2];
    #pragma unroll
    for (int mi = 0; mi < 4; mi++) { acc[mi][0] = (floatx4){0,0,0,0}; acc[mi][1] = (floatx4){0,0,0,0}; }
    #pragma unroll
    for (int ks = 0; ks < 4; ks++) {
      short8 a[4], bb[2];
      #pragma unroll
      for (int mi = 0; mi < 4; mi++) a[mi]  = *(const short8*)&Ps[(mi*16 + lr)*136 + ks*32 + lk];
      #pragma unroll
      for (int ni = 0; ni < 2; ni++) bb[ni] = *(const short8*)&KV[(wave*32 + ni*16 + lr)*136 + ks*32 + lk];
      #pragma unroll
      for (int mi = 0; mi < 4; mi++)
        #pragma unroll
        for (int ni = 0; ni < 2; ni++)
          acc[mi][ni] = __builtin_amdgcn_mfma_f32_16x16x32_bf16(a[mi], bb[ni], acc[mi][ni], 0, 0, 0);
    }
    #pragma unroll
    for (int mi = 0; mi < 4; mi++) {
      #pragma unroll
      for (int ni = 0; ni < 2; ni++) {
        int d = wave*32 + ni*16 + lr;
        #pragma unroll
        for (int q = 0; q < 4; q++) {
          int row = mi*16 + (lane >> 4)*4 + q;
          float o = acc[mi][ni][q] * lrow[row];
          o_r[((size_t)(bh*4 + h)*4096 + kposs[row])*128 + d] = f2bu(o);
        }
      }
    }
  }
}

// ---------------- combine hash rounds ----------------
__global__ __launch_bounds__(256) void k_combine(const ushort* __restrict__ o_r, const float* __restrict__ lse_r,
                                                 ushort* __restrict__ attnbf) {
  int rid = blockIdx.x * 2 + (threadIdx.x >> 7);
  int d = threadIdx.x & 127;
  int bh = rid >> 12, t = rid & 4095;
  int b = bh >> 3, hh = bh & 7;
  size_t base = (size_t)bh * 16384 + t;
  float l0 = lse_r[base], l1 = lse_r[base + 4096], l2 = lse_r[base + 8192], l3 = lse_r[base + 12288];
  float M = fmaxf(fmaxf(l0, l1), fmaxf(l2, l3));
  float e0 = __expf(fmaxf(fminf(l0 - M, 0.f), -80.f));
  float e1 = __expf(fmaxf(fminf(l1 - M, 0.f), -80.f));
  float e2 = __expf(fmaxf(fminf(l2 - M, 0.f), -80.f));
  float e3 = __expf(fmaxf(fminf(l3 - M, 0.f), -80.f));
  float inv = 1.f / (e0 + e1 + e2 + e3);
  float o = e0 * bu2f(o_r[(base         )*128 + d]) + e1 * bu2f(o_r[(base +  4096)*128 + d])
          + e2 * bu2f(o_r[(base +  8192)*128 + d]) + e3 * bu2f(o_r[(base + 12288)*128 + d]);
  attnbf[((size_t)b * kT + t) * kDim + hh*128 + d] = f2bu(o * inv);
}

extern "C" void kernel_launch(void* const* d_in, const int* in_sizes, int n_in,
                              void* d_out, int out_size, void* d_ws, size_t ws_size,
                              hipStream_t stream) {
  (void)in_sizes; (void)n_in; (void)out_size; (void)ws_size;
  const void* x     = d_in[0];
  const void* ln1_g = d_in[1];
  const void* ln1_b = d_in[2];
  const void* Wqk   = d_in[3];
  const void* Wv    = d_in[4];
  const void* Wo    = d_in[5];
  const void* bo    = d_in[6];
  const void* ln2_g = d_in[7];
  const void* ln2_b = d_in[8];
  const void* W1    = d_in[9];
  const void* b1    = d_in[10];
  const void* W2    = d_in[11];
  const void* b2    = d_in[12];
  const void* rot   = d_in[13];

  char* w = (char*)d_ws;
  int*    flag = (int*)w;    w += 256;
  ushort* prm  = (ushort*)w; w += 131072;
  float* x1  = (float*)w;  w += 33554432;
  float* x2  = (float*)w;  w += 33554432;
  ushort* qkh = (ushort*)w; w += 16777216;
  ushort* qkl = (ushort*)w; w += 16777216;
  ushort* vbb = (ushort*)w; w += 16777216;
  ushort* xbf = (ushort*)w; w += 16777216;
  ushort* orb = (ushort*)w; w += 67108864;
  float* lse = (float*)w;  w += 1048576;
  int*   bkt = (int*)w;    w += 1048576;
  int*   stb = (int*)w;    w += 1048576;
  ushort* wtA = (ushort*)w; w += 2097152;
  ushort* wtB = (ushort*)w; w += 2097152;
  ushort* wtC = (ushort*)w; w += 2097152;
  ushort* wt1 = (ushort*)w; w += 8388608;
  ushort* wt2 = (ushort*)w; w += 8388608;
  ushort* rtT = (ushort*)w; w += 32768;

  ushort* pLN1G = prm + 0;     ushort* pLN1B = prm + 2048;
  ushort* pBO   = prm + 4096;  ushort* pLN2G = prm + 6144;
  ushort* pLN2B = prm + 8192;  ushort* pB1   = prm + 10240;
  ushort* pB2   = prm + 18432; ushort* pROT  = prm + 20480;

  k_detect<<<1, 256, 0, stream>>>((const unsigned*)x, flag);
  k_cvt<<<8,   256, 0, stream>>>(flag, ln1_g, pLN1G, 2048);
  k_cvt<<<8,   256, 0, stream>>>(flag, ln1_b, pLN1B, 2048);
  k_cvt<<<8,   256, 0, stream>>>(flag, bo,    pBO,   2048);
  k_cvt<<<8,   256, 0, stream>>>(flag, ln2_g, pLN2G, 2048);
  k_cvt<<<8,   256, 0, stream>>>(flag, ln2_b, pLN2B, 2048);
  k_cvt<<<32,  256, 0, stream>>>(flag, b1,    pB1,   8192);
  k_cvt<<<8,   256, 0, stream>>>(flag, b2,    pB2,   2048);
  k_cvt<<<128, 256, 0, stream>>>(flag, rot,   pROT,  32768);
  k_init_any<<<8192, 256, 0, stream>>>(flag, x, x1, x2);

  for (int d = 0; d < 2; d++) {
    k_transpose2<<<dim3(32, 32),  256, 0, stream>>>(flag,
        (const char*)Wqk + (size_t)d*1048576*2, (const char*)Wqk + (size_t)d*1048576*4, wtA, 1024, 1024);
    k_transpose2<<<dim3(32, 32),  256, 0, stream>>>(flag,
        (const char*)Wv  + (size_t)d*1048576*2, (const char*)Wv  + (size_t)d*1048576*4, wtB, 1024, 1024);
    k_transpose2<<<dim3(32, 32),  256, 0, stream>>>(flag,
        (const char*)Wo  + (size_t)d*1048576*2, (const char*)Wo  + (size_t)d*1048576*4, wtC, 1024, 1024);
    k_transpose2<<<dim3(128, 32), 256, 0, stream>>>(flag,
        (const char*)W1  + (size_t)d*4194304*2, (const char*)W1  + (size_t)d*4194304*4, wt1, 1024, 4096);
    k_transpose2<<<dim3(32, 128), 256, 0, stream>>>(flag,
        (const char*)W2  + (size_t)d*4194304*2, (const char*)W2  + (size_t)d*4194304*4, wt2, 4096, 1024);
    k_rot_t<<<1, 256, 0, stream>>>(pROT + (size_t)d * 16384, rtT);

    k_ln<<<8192, 256, 0, stream>>>(x2, pLN1G + d*1024, pLN1B + d*1024, xbf);
    k_gemm<<<dim3(8, 64), 256, 0, stream>>>(xbf, wtA, nullptr, nullptr, qkh, qkl, 8192, 1024, 1024, 5);
    k_gemm<<<dim3(8, 64), 256, 0, stream>>>(xbf, wtB, nullptr, nullptr, vbb, nullptr, 8192, 1024, 1024, 3);
    k_bucket_mfma<<<dim3(64, 16), 256, 0, stream>>>(qkh, qkl, rtT, bkt);
    k_sort<<<64, 256, 0, stream>>>(bkt, stb);
    k_attn<<<4096, 256, 0, stream>>>(qkh, vbb, stb, orb, lse);
    k_combine<<<32768, 256, 0, stream>>>(orb, lse, xbf);
    k_gemm<<<dim3(8, 64), 256, 0, stream>>>(xbf, wtC, pBO + d*1024, x1, nullptr, nullptr, 8192, 1024, 1024, 1);
    k_ln<<<8192, 256, 0, stream>>>(x1, pLN2G + d*1024, pLN2B + d*1024, xbf);
    k_gemm<<<dim3(32, 64), 256, 0, stream>>>(xbf, wt1, pB1 + d*4096, nullptr, orb, nullptr, 8192, 4096, 1024, 2);
    k_gemm<<<dim3(8, 64), 256, 0, stream>>>(orb, wt2, pB2 + d*1024, x2, nullptr, nullptr, 8192, 1024, 4096, 1);
  }
  k_final_any<<<8192, 256, 0, stream>>>(flag, x1, x2, d_out);
}